// Round 6
// baseline (1615.433 us; speedup 1.0000x reference)
//
#include <hip/hip_runtime.h>
#include <math.h>
#include <cstddef>

#define NNODES 32768
#define NEDGES 262144
#define NB 32
#define CH 8192  // epilogue chunk rows
#define RSPLIT 16

typedef _Float16 f16x4 __attribute__((ext_vector_type(4)));
typedef _Float16 f16x8 __attribute__((ext_vector_type(8)));
typedef float f32x4 __attribute__((ext_vector_type(4)));

__device__ __forceinline__ void load8f(const float* p, float* o) {
  float4 a = *reinterpret_cast<const float4*>(p);
  float4 b = *reinterpret_cast<const float4*>(p + 4);
  o[0] = a.x; o[1] = a.y; o[2] = a.z; o[3] = a.w;
  o[4] = b.x; o[5] = b.y; o[6] = b.z; o[7] = b.w;
}

__global__ void GraphEncoder_82575041233261_kernel() {}

__global__ void fill_f32(float* p, float v, int n) {
  int i = blockIdx.x * blockDim.x + threadIdx.x;
  if (i < n) p[i] = v;
}
__global__ void fill_i32(int* p, int v, int n) {
  int i = blockIdx.x * blockDim.x + threadIdx.x;
  if (i < n) p[i] = v;
}
__global__ void fill_dc(float* dis, int* cnt, int n) {
  int i = blockIdx.x * blockDim.x + threadIdx.x;
  if (i < n) { dis[i] = 0.f; cnt[i] = 0; }
}

__global__ void edge_init(const int* __restrict__ ei, const float* __restrict__ ew,
                          int* ei0, int* ei1, float* ewf, int* emask) {
  int e = blockIdx.x * blockDim.x + threadIdx.x;
  if (e >= NEDGES) return;
  ei0[e] = ei[e];
  ei1[e] = ei[NEDGES + e];
  ewf[e] = ew[e];
  emask[e] = 1;
}

// ================= split-f16 MFMA GEMM machinery =================
struct MTile {
  _Float16 Ah[128][40];
  _Float16 Al[128][40];
  _Float16 Bh[128][40];
  _Float16 Bl[128][40];
};

__device__ __forceinline__ void stageA(MTile& sm, const float* __restrict__ A,
                                       int lda, int tid) {
#pragma unroll
  for (int i = 0; i < 4; i++) {
    int flat = tid + i * 256;            // 1024 float4 = 128 rows x 32 k
    int r = flat >> 3, c4 = (flat & 7) << 2;
    float4 v = *reinterpret_cast<const float4*>(A + (size_t)r * lda + c4);
    _Float16 h0 = (_Float16)v.x, h1 = (_Float16)v.y;
    _Float16 h2 = (_Float16)v.z, h3 = (_Float16)v.w;
    f16x4 hv = {h0, h1, h2, h3};
    f16x4 lv = {(_Float16)(v.x - (float)h0), (_Float16)(v.y - (float)h1),
                (_Float16)(v.z - (float)h2), (_Float16)(v.w - (float)h3)};
    *reinterpret_cast<f16x4*>(&sm.Ah[r][c4]) = hv;
    *reinterpret_cast<f16x4*>(&sm.Al[r][c4]) = lv;
  }
}

__device__ __forceinline__ void stageB(MTile& sm, const _Float16* __restrict__ th,
                                       const _Float16* __restrict__ tl, int Kw,
                                       int tid) {
#pragma unroll
  for (int i = 0; i < 4; i++) {
    int flat = tid + i * 256;            // 1024 chunks of 8 halfs (hi then lo)
    int sel = flat >> 9;                 // uniform per i
    int cc = (flat >> 2) & 127, kc = (flat & 3) << 3;
    const _Float16* s = (sel ? tl : th) + (size_t)cc * Kw + kc;
    f16x8 v = *reinterpret_cast<const f16x8*>(s);
    if (sel)
      *reinterpret_cast<f16x8*>(&sm.Bl[cc][kc]) = v;
    else
      *reinterpret_cast<f16x8*>(&sm.Bh[cc][kc]) = v;
  }
}

__device__ __forceinline__ void mcompute(MTile& sm, f32x4 acc[4][4], int wm,
                                         int wn, int fr, int fq) {
  f16x8 ah[4], al[4], bh[4], bl[4];
#pragma unroll
  for (int m = 0; m < 4; m++) {
    ah[m] = *reinterpret_cast<const f16x8*>(&sm.Ah[wm + m * 16 + fr][fq * 8]);
    al[m] = *reinterpret_cast<const f16x8*>(&sm.Al[wm + m * 16 + fr][fq * 8]);
  }
#pragma unroll
  for (int nn = 0; nn < 4; nn++) {
    bh[nn] = *reinterpret_cast<const f16x8*>(&sm.Bh[wn + nn * 16 + fr][fq * 8]);
    bl[nn] = *reinterpret_cast<const f16x8*>(&sm.Bl[wn + nn * 16 + fr][fq * 8]);
  }
#pragma unroll
  for (int m = 0; m < 4; m++)
#pragma unroll
    for (int nn = 0; nn < 4; nn++) {
      acc[m][nn] = __builtin_amdgcn_mfma_f32_16x16x32_f16(ah[m], bh[nn], acc[m][nn], 0, 0, 0);
      acc[m][nn] = __builtin_amdgcn_mfma_f32_16x16x32_f16(ah[m], bl[nn], acc[m][nn], 0, 0, 0);
      acc[m][nn] = __builtin_amdgcn_mfma_f32_16x16x32_f16(al[m], bh[nn], acc[m][nn], 0, 0, 0);
    }
}

// C[n,M] = A[n,K] @ W + bias (relu optional). W pre-split transposed WT[2][M][K].
__global__ __launch_bounds__(256) void mgemm(
    const float* __restrict__ A, const _Float16* __restrict__ WT,
    const float* __restrict__ bias, float* __restrict__ C,
    int n, int K, int M, int relu) {
  __shared__ MTile sm;
  const int tid = threadIdx.x;
  const int lane = tid & 63, w = tid >> 6;
  const int wm = (w >> 1) << 6, wn = (w & 1) << 6;
  const int fr = lane & 15, fq = lane >> 4;
  const int row0 = blockIdx.x * 128, col0 = blockIdx.y * 128;
  const _Float16* th = WT + (size_t)col0 * K;
  const _Float16* tl = WT + (size_t)M * K + (size_t)col0 * K;
  const float* Ab = A + (size_t)row0 * K;
  f32x4 acc[4][4];
#pragma unroll
  for (int m = 0; m < 4; m++)
#pragma unroll
    for (int nn = 0; nn < 4; nn++) acc[m][nn] = (f32x4){0.f, 0.f, 0.f, 0.f};
  for (int kt = 0; kt < K; kt += 32) {
    stageA(sm, Ab + kt, K, tid);
    stageB(sm, th + kt, tl + kt, K, tid);
    __syncthreads();
    mcompute(sm, acc, wm, wn, fr, fq);
    __syncthreads();
  }
#pragma unroll
  for (int nn = 0; nn < 4; nn++) {
    const int col = col0 + wn + nn * 16 + fr;
    const float b = bias ? bias[col] : 0.f;
#pragma unroll
    for (int m = 0; m < 4; m++)
#pragma unroll
      for (int j = 0; j < 4; j++) {
        int row = row0 + wm + m * 16 + fq * 4 + j;
        float v = acc[m][nn][j] + b;
        if (relu) v = fmaxf(v, 0.f);
        C[(size_t)row * M + col] = v;
      }
  }
}

// attn epilogue GEMM, MFMA version. BN=128 = one head per col-block.
__global__ __launch_bounds__(256) void mattn(
    const float* __restrict__ Z, const float* __restrict__ WS,
    const float* __restrict__ XLv, const float* __restrict__ XW,
    const float* __restrict__ DEN, const _Float16* __restrict__ WvT,
    const _Float16* __restrict__ EWmT, const _Float16* __restrict__ SwT,
    const float* __restrict__ vb, const float* __restrict__ eb,
    const float* __restrict__ sb, float* __restrict__ ATTN, int rowBase) {
  __shared__ MTile sm;
  const int tid = threadIdx.x;
  const int lane = tid & 63, w = tid >> 6;
  const int wm = (w >> 1) << 6, wn = (w & 1) << 6;
  const int fr = lane & 15, fq = lane >> 4;
  const int h = blockIdx.y;
  const int col0 = h << 7;
  const int rloc0 = blockIdx.x * 128;
  const int row0 = rowBase + rloc0;
  f32x4 acc[4][4];
#pragma unroll
  for (int m = 0; m < 4; m++)
#pragma unroll
    for (int nn = 0; nn < 4; nn++) acc[m][nn] = (f32x4){0.f, 0.f, 0.f, 0.f};
  // phase A: K=128 over Z (head slice)
  {
    const float* Ab = Z + (size_t)row0 * 512 + col0;
    const _Float16* th = WvT + (size_t)col0 * 128;
    const _Float16* tl = WvT + (size_t)512 * 128 + (size_t)col0 * 128;
    for (int kt = 0; kt < 128; kt += 32) {
      stageA(sm, Ab + kt, 512, tid);
      stageB(sm, th + kt, tl + kt, 128, tid);
      __syncthreads();
      mcompute(sm, acc, wm, wn, fr, fq);
      __syncthreads();
    }
  }
  // phase B: K=64 over WS (head slice)
  {
    const float* Ab = WS + (size_t)row0 * 256 + (h << 6);
    const _Float16* th = EWmT + (size_t)col0 * 64;
    const _Float16* tl = EWmT + (size_t)512 * 64 + (size_t)col0 * 64;
    for (int kt = 0; kt < 64; kt += 32) {
      stageA(sm, Ab + kt, 256, tid);
      stageB(sm, th + kt, tl + kt, 64, tid);
      __syncthreads();
      mcompute(sm, acc, wm, wn, fr, fq);
      __syncthreads();
    }
  }
  // mid: den scaling + biases
  {
    float vbe[4], sbv[4];
#pragma unroll
    for (int nn = 0; nn < 4; nn++) {
      int col = col0 + wn + nn * 16 + fr;
      vbe[nn] = vb[col] + eb[col];
      sbv[nn] = sb[col];
    }
#pragma unroll
    for (int m = 0; m < 4; m++)
#pragma unroll
      for (int j = 0; j < 4; j++) {
        int row = row0 + wm + m * 16 + fq * 4 + j;
        float d = DEN[(size_t)row * 4 + h];
        float inv = 1.f / (d + 1e-16f);
#pragma unroll
        for (int nn = 0; nn < 4; nn++)
          acc[m][nn][j] = (acc[m][nn][j] + d * vbe[nn]) * inv + sbv[nn];
      }
  }
  // phase C: K=128 over XL (skip branch), accumulates post-scaling
  {
    const float* Ab = XLv + (size_t)row0 * 128;
    const _Float16* th = SwT + (size_t)col0 * 128;
    const _Float16* tl = SwT + (size_t)512 * 128 + (size_t)col0 * 128;
    for (int kt = 0; kt < 128; kt += 32) {
      stageA(sm, Ab + kt, 128, tid);
      stageB(sm, th + kt, tl + kt, 128, tid);
      __syncthreads();
      mcompute(sm, acc, wm, wn, fr, fq);
      __syncthreads();
    }
  }
#pragma unroll
  for (int nn = 0; nn < 4; nn++) {
    int col = col0 + wn + nn * 16 + fr;
#pragma unroll
    for (int m = 0; m < 4; m++)
#pragma unroll
      for (int j = 0; j < 4; j++) {
        int rl = rloc0 + wm + m * 16 + fq * 4 + j;
        float v = acc[m][nn][j] + XW[(size_t)(rowBase + rl) * 128 + (col & 127)];
        ATTN[(size_t)rl * 512 + col] = v;
      }
  }
}

// ---- merged weight prep: split fp32 W[K][M] -> WT[2][M][K] f16 for all 5 ----
__global__ void wsplit_all(const float* __restrict__ lw, int K0,
                           const float* __restrict__ vw, const float* __restrict__ ew,
                           const float* __restrict__ sw, const float* __restrict__ trw,
                           _Float16* __restrict__ lwT, _Float16* __restrict__ WvT,
                           _Float16* __restrict__ EWmT, _Float16* __restrict__ SwT,
                           _Float16* __restrict__ TrT) {
  int idx = blockIdx.x * 256 + threadIdx.x;
  const float* W; _Float16* T; int K, msh, loc;
  const int s0 = K0 << 7;
  if (idx < s0) { W = lw; T = lwT; K = K0; msh = 7; loc = idx; }
  else if (idx < s0 + 65536) { W = vw; T = WvT; K = 128; msh = 9; loc = idx - s0; }
  else if (idx < s0 + 98304) { W = ew; T = EWmT; K = 64; msh = 9; loc = idx - s0 - 65536; }
  else if (idx < s0 + 163840) { W = sw; T = SwT; K = 128; msh = 9; loc = idx - s0 - 98304; }
  else if (idx < s0 + 229376) { W = trw; T = TrT; K = 512; msh = 7; loc = idx - s0 - 163840; }
  else return;
  int M = 1 << msh;
  int k = loc >> msh, m2 = loc & (M - 1);
  float v = W[loc];
  _Float16 hh = (_Float16)v;
  T[(size_t)m2 * K + k] = hh;
  T[(size_t)M * K + (size_t)m2 * K + k] = (_Float16)(v - (float)hh);
}

// ---- merged folded-weight prep (float4-vectorized inner loops) ----
__global__ __launch_bounds__(256) void prep_all(
    const float* __restrict__ Wq, const float* __restrict__ Wk,
    const float* __restrict__ EWm, const float* __restrict__ bq,
    const float* __restrict__ bk, const float* __restrict__ eb,
    _Float16* __restrict__ CtT, _Float16* __restrict__ BtT,
    float* __restrict__ gb, float* __restrict__ WCR, float* __restrict__ CC) {
  int idx = blockIdx.x * 256 + threadIdx.x;
  if (idx < 65536) {
    int cin = idx >> 9, r = idx & 511, h = r >> 7, co = r & 127;
    const float4* a4 = reinterpret_cast<const float4*>(Wq + cin * 512 + h * 128);
    const float4* b4 = reinterpret_cast<const float4*>(Wk + co * 512 + h * 128);
    float acc = 0.f;
#pragma unroll 8
    for (int c = 0; c < 32; c++) {
      float4 a = a4[c], b = b4[c];
      acc += a.x * b.x + a.y * b.y + a.z * b.z + a.w * b.w;
    }
    _Float16 hh = (_Float16)acc;
    CtT[(size_t)r * 128 + cin] = hh;
    CtT[(size_t)512 * 128 + (size_t)r * 128 + cin] = (_Float16)(acc - (float)hh);
  } else if (idx < 98304) {
    int t = idx - 65536;
    int cin = t >> 8, r = t & 255, h = r >> 6, f = r & 63;
    const float4* a4 = reinterpret_cast<const float4*>(Wq + cin * 512 + h * 128);
    const float4* b4 = reinterpret_cast<const float4*>(EWm + f * 512 + h * 128);
    float acc = 0.f;
#pragma unroll 8
    for (int c = 0; c < 32; c++) {
      float4 a = a4[c], b = b4[c];
      acc += a.x * b.x + a.y * b.y + a.z * b.z + a.w * b.w;
    }
    _Float16 hh = (_Float16)acc;
    BtT[(size_t)r * 128 + cin] = hh;
    BtT[(size_t)256 * 128 + (size_t)r * 128 + cin] = (_Float16)(acc - (float)hh);
    if (cin == 0) {
      const float4* c4 = reinterpret_cast<const float4*>(bq + h * 128);
      float s = 0.f;
#pragma unroll 8
      for (int c = 0; c < 32; c++) {
        float4 a = b4[c], b = c4[c];
        s += a.x * b.x + a.y * b.y + a.z * b.z + a.w * b.w;
      }
      gb[r] = s;
    }
  } else if (idx < 99328) {
    int tid = idx - 98304;
    int cin = tid >> 3, j = tid & 7, h2 = j & 3, isR = j >> 2;
    float acc = 0.f;
    if (isR) {
      for (int c = 0; c < 128; c++)
        acc += Wk[cin * 512 + h2 * 128 + c] * bq[h2 * 128 + c];
    } else {
      for (int c = 0; c < 128; c++)
        acc += Wq[cin * 512 + h2 * 128 + c] * (bk[h2 * 128 + c] + eb[h2 * 128 + c]);
    }
    WCR[cin * 8 + j] = acc;
    if (tid < 4) {
      float s = 0.f;
      for (int c = 0; c < 128; c++)
        s += bq[tid * 128 + c] * (bk[tid * 128 + c] + eb[tid * 128 + c]);
      CC[tid] = s;
    }
  }
}

// SCV[node, j] = XL[node]·WCR[:,j] (+CC for j<4); float4 loads
__global__ __launch_bounds__(256) void node_scalars(const float* __restrict__ XL,
                                                    const float* __restrict__ WCR,
                                                    const float* __restrict__ CC,
                                                    float* __restrict__ SCV, int n) {
  int t = blockIdx.x * 256 + threadIdx.x;
  if (t >= n * 8) return;
  int node = t >> 3, j = t & 7;
  const float4* x4 = reinterpret_cast<const float4*>(XL + (size_t)node * 128);
  float acc = (j < 4) ? CC[j] : 0.f;
#pragma unroll 8
  for (int c = 0; c < 32; c++) {
    float4 v = x4[c];
    acc += v.x * WCR[(c * 4) * 8 + j] + v.y * WCR[(c * 4 + 1) * 8 + j] +
           v.z * WCR[(c * 4 + 2) * 8 + j] + v.w * WCR[(c * 4 + 3) * 8 + j];
  }
  SCV[t] = acc;
}

// merged degree + indegree count
__global__ void deg_cnt(const int* __restrict__ ei0, const int* __restrict__ ei1,
                        const int* __restrict__ emask, float* deg, int* cnt) {
  int e = blockIdx.x * blockDim.x + threadIdx.x;
  if (e >= NEDGES) return;
  if (emask[e]) {
    atomicAdd(&deg[ei0[e]], 1.0f);
    atomicAdd(&cnt[ei1[e]], 1);
  }
}

// ---- parallel 3-phase exclusive scan over cnt (n multiple of 1024) ----
__global__ __launch_bounds__(256) void scan_p1(const int* __restrict__ cnt,
                                               float* __restrict__ dis,
                                               int* __restrict__ toff,
                                               int* __restrict__ bsum) {
  const int b = blockIdx.x, tid = threadIdx.x;
  const int gi = b * 1024 + tid * 4;
  int4 c = *reinterpret_cast<const int4*>(cnt + gi);
  float4 d = *reinterpret_cast<const float4*>(dis + gi);
  float4 dr;
  dr.x = d.x > 0.f ? rsqrtf(d.x) : 0.f;
  dr.y = d.y > 0.f ? rsqrtf(d.y) : 0.f;
  dr.z = d.z > 0.f ? rsqrtf(d.z) : 0.f;
  dr.w = d.w > 0.f ? rsqrtf(d.w) : 0.f;
  *reinterpret_cast<float4*>(dis + gi) = dr;
  int s = c.x + c.y + c.z + c.w;
  __shared__ int sh[256];
  sh[tid] = s;
  __syncthreads();
  for (int dstep = 1; dstep < 256; dstep <<= 1) {
    int t = (tid >= dstep) ? sh[tid - dstep] : 0;
    __syncthreads();
    sh[tid] += t;
    __syncthreads();
  }
  toff[b * 256 + tid] = sh[tid] - s;  // exclusive within block
  if (tid == 255) bsum[b] = sh[255];
}
__global__ void scan_p2(const int* __restrict__ bsum, int* __restrict__ boff,
                        int nb, int* __restrict__ indptr, int n) {
  if (threadIdx.x == 0) {
    int run = 0;
    for (int i = 0; i < nb; i++) { boff[i] = run; run += bsum[i]; }
    indptr[n] = run;
  }
}
__global__ __launch_bounds__(256) void scan_p3(const int* __restrict__ cnt,
                                               const int* __restrict__ toff,
                                               const int* __restrict__ boff,
                                               int* __restrict__ indptr,
                                               int* __restrict__ cursor) {
  const int b = blockIdx.x, tid = threadIdx.x;
  const int gi = b * 1024 + tid * 4;
  int4 c = *reinterpret_cast<const int4*>(cnt + gi);
  int run = boff[b] + toff[b * 256 + tid];
  int4 o;
  o.x = run;
  o.y = run + c.x;
  o.z = o.y + c.y;
  o.w = o.z + c.z;
  *reinterpret_cast<int4*>(indptr + gi) = o;
  *reinterpret_cast<int4*>(cursor + gi) = o;
}

// CSR fill, packed 16B records: PCK[p]={src, e, bits(dis[src]*ewf[e]), 0}
__global__ void csr_fill(const int* __restrict__ ei0, const int* __restrict__ ei1,
                         const int* __restrict__ emask, const float* __restrict__ ewf,
                         const float* __restrict__ dis, int* cursor,
                         int4* __restrict__ pck) {
  int e = blockIdx.x * blockDim.x + threadIdx.x;
  if (e >= NEDGES) return;
  if (!emask[e]) return;
  int p = atomicAdd(&cursor[ei1[e]], 1);
  int r = ei0[e];
  int4 rec;
  rec.x = r;
  rec.y = e;
  rec.z = __float_as_int(dis[r] * ewf[e]);
  rec.w = 0;
  pck[p] = rec;
}

// ---- light attention pass: one wave per destination node, online softmax.
// 4-buffer software pipeline: prologue issues 4 edges' gathers; each compute
// is followed by the load 4 edges ahead (clamped address, unconditional) so
// ~600cy gather latency is covered by ~3 edge-computes. Math identical to
// the defer-max version (rescale only when alpha > m+8).
#define ATTN_LOAD(XR, EA4, idx)                                              \
  do {                                                                       \
    const int ii_ = min((idx), cnt - 1);                                     \
    const int rr_ = __shfl(rec.x, ii_);                                      \
    const int ee_ = __shfl(rec.y, ii_);                                      \
    load8f(XLv + (size_t)rr_ * 128 + t16 * 8, XR);                           \
    EA4 = *reinterpret_cast<const float4*>(EA + (size_t)ee_ * 64 + t16 * 4); \
  } while (0)

#define ATTN_COMPUTE(XR, EA4, idx)                                           \
  do {                                                                       \
    const float rowS_ = __shfl(rsv, (h << 4) + (idx));                       \
    const float dn_ = __shfl(dnl, (idx));                                    \
    float p_ = 0.f;                                                          \
    _Pragma("unroll") for (int j = 0; j < 8; j++) p_ += u8[j] * XR[j];       \
    p_ += g4.x * EA4.x + g4.y * EA4.y + g4.z * EA4.z + g4.w * EA4.w;         \
    p_ += __shfl_xor(p_, 1);                                                 \
    p_ += __shfl_xor(p_, 2);                                                 \
    p_ += __shfl_xor(p_, 4);                                                 \
    p_ += __shfl_xor(p_, 8);                                                 \
    const float alpha_ = (p_ + colS + rowS_) * rs;                           \
    if (alpha_ > m + 8.f) {                                                  \
      const float sc_ = __expf(m - alpha_);                                  \
      den *= sc_;                                                            \
      _Pragma("unroll") for (int j = 0; j < 8; j++) z8[j] *= sc_;            \
      w4[0] *= sc_; w4[1] *= sc_; w4[2] *= sc_; w4[3] *= sc_;                \
      m = alpha_;                                                            \
    }                                                                        \
    const float a_ = __expf(alpha_ - m);                                     \
    den += a_;                                                               \
    _Pragma("unroll") for (int j = 0; j < 8; j++) z8[j] += a_ * XR[j];       \
    w4[0] += a_ * EA4.x;                                                     \
    w4[1] += a_ * EA4.y;                                                     \
    w4[2] += a_ * EA4.z;                                                     \
    w4[3] += a_ * EA4.w;                                                     \
    _Pragma("unroll") for (int j = 0; j < 8; j++) xw8[j] += dn_ * XR[j];     \
  } while (0)

__global__ __launch_bounds__(256) void fused_attn_light(
    const int4* __restrict__ PCK, const int* __restrict__ indptr,
    const float* __restrict__ EA, const float* __restrict__ XLv,
    float* U, float* G, const float* __restrict__ SCVv,
    const float* __restrict__ DISv, float* __restrict__ XW,
    float* __restrict__ DEN) {
  const int w = threadIdx.x >> 6, lane = threadIdx.x & 63;
  const int h = lane >> 4, t16 = lane & 15;
  const int col = blockIdx.x * 4 + w;
  float u8[8];
  load8f(U + (size_t)col * 512 + lane * 8, u8);
  float4 g4 = *reinterpret_cast<const float4*>(G + (size_t)col * 256 + lane * 4);
  const float colS = SCVv[col * 8 + h];
  const float dcol = DISv[col];
  const int beg = indptr[col], end = indptr[col + 1];
  const float rs = 0.08838834764831845f;  // 1/sqrt(128)
  float m = -3.0e38f, den = 0.f;
  float z8[8] = {0.f, 0.f, 0.f, 0.f, 0.f, 0.f, 0.f, 0.f};
  float w4[4] = {0.f, 0.f, 0.f, 0.f};
  float xw8[8] = {0.f, 0.f, 0.f, 0.f, 0.f, 0.f, 0.f, 0.f};
  for (int base = beg; base < end; base += 16) {
    const int cnt = min(16, end - base);
    const int li = base + min(t16, cnt - 1);
    const int4 rec = PCK[li];
    const float dnl = __int_as_float(rec.z);
    const float rsv = SCVv[(size_t)rec.x * 8 + 4 + h];
    float xrA[8], xrB[8], xrC[8], xrD[8];
    float4 eaA, eaB, eaC, eaD;
    ATTN_LOAD(xrA, eaA, 0);
    ATTN_LOAD(xrB, eaB, 1);
    ATTN_LOAD(xrC, eaC, 2);
    ATTN_LOAD(xrD, eaD, 3);
    int i = 0;
    for (; i + 4 <= cnt; i += 4) {
      ATTN_COMPUTE(xrA, eaA, i);
      ATTN_LOAD(xrA, eaA, i + 4);
      ATTN_COMPUTE(xrB, eaB, i + 1);
      ATTN_LOAD(xrB, eaB, i + 5);
      ATTN_COMPUTE(xrC, eaC, i + 2);
      ATTN_LOAD(xrC, eaC, i + 6);
      ATTN_COMPUTE(xrD, eaD, i + 3);
      ATTN_LOAD(xrD, eaD, i + 7);
    }
    if (i < cnt) ATTN_COMPUTE(xrA, eaA, i);
    if (i + 1 < cnt) ATTN_COMPUTE(xrB, eaB, i + 1);
    if (i + 2 < cnt) ATTN_COMPUTE(xrC, eaC, i + 2);
  }
  float4 o1, o2;
  o1.x = z8[0]; o1.y = z8[1]; o1.z = z8[2]; o1.w = z8[3];
  o2.x = z8[4]; o2.y = z8[5]; o2.z = z8[6]; o2.w = z8[7];
  *reinterpret_cast<float4*>(U + (size_t)col * 512 + lane * 8) = o1;
  *reinterpret_cast<float4*>(U + (size_t)col * 512 + lane * 8 + 4) = o2;
  float4 ow;
  ow.x = w4[0]; ow.y = w4[1]; ow.z = w4[2]; ow.w = w4[3];
  *reinterpret_cast<float4*>(G + (size_t)col * 256 + lane * 4) = ow;
  if (h == 0) {  // degree-norm branch: channels t16*8..t16*8+8
    float4 x1, x2;
    x1.x = xw8[0] * dcol; x1.y = xw8[1] * dcol; x1.z = xw8[2] * dcol; x1.w = xw8[3] * dcol;
    x2.x = xw8[4] * dcol; x2.y = xw8[5] * dcol; x2.z = xw8[6] * dcol; x2.w = xw8[7] * dcol;
    *reinterpret_cast<float4*>(XW + (size_t)col * 128 + t16 * 8) = x1;
    *reinterpret_cast<float4*>(XW + (size_t)col * 128 + t16 * 8 + 4) = x2;
  }
  if (t16 == 0) DEN[col * 4 + h] = den;
}

// ---- batchnorm (in-place) ----
__global__ __launch_bounds__(256) void bn_accum(const float* __restrict__ x,
                                                float* __restrict__ part1,
                                                float* __restrict__ part2, int n) {
  __shared__ float sh1[256], sh2[256];
  int c = threadIdx.x & 127;
  int half = threadIdx.x >> 7;
  float a = 0.f, b = 0.f;
  for (int i = blockIdx.x * 2 + half; i < n; i += gridDim.x * 2) {
    float v = x[(size_t)i * 128 + c];
    a += v;
    b += v * v;
  }
  sh1[threadIdx.x] = a;
  sh2[threadIdx.x] = b;
  __syncthreads();
  if (half == 0) {
    part1[blockIdx.x * 128 + c] = a + sh1[threadIdx.x + 128];
    part2[blockIdx.x * 128 + c] = b + sh2[threadIdx.x + 128];
  }
}
__global__ void bn_final(const float* __restrict__ part1, const float* __restrict__ part2,
                         float* mu, float* rstd, int n) {
  int c = threadIdx.x;
  if (c >= 128) return;
  float s1 = 0.f, s2 = 0.f;
#pragma unroll 8
  for (int b = 0; b < 256; b++) {
    s1 += part1[b * 128 + c];
    s2 += part2[b * 128 + c];
  }
  float m = s1 / (float)n;
  mu[c] = m;
  float var = s2 / (float)n - m * m;
  rstd[c] = rsqrtf(var + 1e-5f);
}
__global__ void bn_apply(float* x, const float* __restrict__ mu,
                         const float* __restrict__ rstd, const float* __restrict__ g,
                         const float* __restrict__ b, int n) {
  int t = blockIdx.x * blockDim.x + threadIdx.x;
  if (t >= n * 128) return;
  int c = t & 127;
  x[t] = g[c] * (x[t] - mu[c]) * rstd[c] + b[c];
}

// ---- pooling ----
__global__ void wnorm_kernel(const float* __restrict__ w, float* wn) {
  __shared__ float s[128];
  int t = threadIdx.x;
  float v = w[t];
  s[t] = v * v;
  __syncthreads();
  for (int st = 64; st > 0; st >>= 1) {
    if (t < st) s[t] += s[t + st];
    __syncthreads();
  }
  if (t == 0) wn[0] = sqrtf(s[0]) + 1e-16f;
}
__global__ void score_kernel(const float* __restrict__ h, const float* __restrict__ w,
                             const float* __restrict__ wn, float* s, int n) {
  int i = blockIdx.x * blockDim.x + threadIdx.x;
  if (i >= n) return;
  const float4* hr = reinterpret_cast<const float4*>(h + (size_t)i * 128);
  const float4* wr = reinterpret_cast<const float4*>(w);
  float d = 0.f;
  for (int c = 0; c < 32; c++) {
    float4 a = hr[c], b = wr[c];
    d += a.x * b.x + a.y * b.y + a.z * b.z + a.w * b.w;
  }
  s[i] = tanhf(d / wn[0]);
}
__global__ __launch_bounds__(512) void topk_kernel(const float* __restrict__ s,
                                                   float* gateVal, int* selIdx,
                                                   int* newid, int M) {
  __shared__ float sv[1024];
  __shared__ int si[1024];
  const int g = blockIdx.x;
  const int k = M >> 1;
  for (int t = threadIdx.x; t < 1024; t += 512) {
    if (t < M) {
      sv[t] = s[(size_t)g * M + t];
      si[t] = t;
    } else {
      sv[t] = -3.4e38f;
      si[t] = 0x7fffffff;
    }
  }
  __syncthreads();
  for (int kk = 2; kk <= 1024; kk <<= 1) {
    for (int j = kk >> 1; j > 0; j >>= 1) {
      for (int t = threadIdx.x; t < 1024; t += 512) {
        int p = t ^ j;
        if (p > t) {
          float va = sv[t], vb2 = sv[p];
          int ia = si[t], ib = si[p];
          bool beforeBA = (vb2 > va) || (vb2 == va && ib < ia);
          bool beforeAB = (va > vb2) || (va == vb2 && ia < ib);
          bool dir = ((t & kk) == 0);
          bool sw = dir ? beforeBA : beforeAB;
          if (sw) {
            sv[t] = vb2;
            sv[p] = va;
            si[t] = ib;
            si[p] = ia;
          }
        }
      }
      __syncthreads();
    }
  }
  for (int j = threadIdx.x; j < k; j += 512) {
    int oldg = g * M + si[j];
    int newg = g * k + j;
    gateVal[newg] = sv[j];
    selIdx[newg] = oldg;
    newid[oldg] = newg;
  }
}
__global__ void gate_kernel(const float* __restrict__ hOld, const float* __restrict__ gv,
                            const int* __restrict__ sel, float* __restrict__ hNew,
                            int nNew) {
  int t = blockIdx.x * blockDim.x + threadIdx.x;
  if (t >= nNew * 128) return;
  int i = t >> 7, c = t & 127;
  hNew[t] = hOld[(size_t)sel[i] * 128 + c] * gv[i];
}
__global__ void relabel_kernel(int* ei0, int* ei1, float* ewf, int* emask,
                               const int* __restrict__ newid) {
  int e = blockIdx.x * blockDim.x + threadIdx.x;
  if (e >= NEDGES) return;
  int nr = newid[ei0[e]];
  int nc = newid[ei1[e]];
  int keep = (nr >= 0 && nc >= 0 && emask[e]) ? 1 : 0;
  ei0[e] = keep ? nr : 0;
  ei1[e] = keep ? nc : 0;
  ewf[e] = keep ? ewf[e] : 0.f;
  emask[e] = keep;
}
// ---- reps: split row-reduction for occupancy ----
__global__ void reps_partial(const float* __restrict__ h, float* __restrict__ rpart,
                             int k) {
  int g = blockIdx.x / RSPLIT, s = blockIdx.x % RSPLIT;
  int c = threadIdx.x;
  int per = k / RSPLIT;
  int j0 = s * per;
  float mx = -3.4e38f, sm = 0.f;
  for (int j = j0; j < j0 + per; j++) {
    float v = h[(size_t)(g * k + j) * 128 + c];
    mx = fmaxf(mx, v);
    sm += v;
  }
  rpart[(size_t)(g * RSPLIT + s) * 256 + c] = mx;
  rpart[(size_t)(g * RSPLIT + s) * 256 + 128 + c] = sm;
}
__global__ void reps_final(const float* __restrict__ rpart, float* __restrict__ rep,
                           int k) {
  int g = blockIdx.x, c = threadIdx.x;
  float mx = -3.4e38f, sm = 0.f;
  for (int s = 0; s < RSPLIT; s++) {
    mx = fmaxf(mx, rpart[(size_t)(g * RSPLIT + s) * 256 + c]);
    sm += rpart[(size_t)(g * RSPLIT + s) * 256 + 128 + c];
  }
  rep[g * 256 + c] = mx;
  rep[g * 256 + 128 + c] = sm / (float)k;
}
__global__ void final_out(const float* __restrict__ r0, const float* __restrict__ r1,
                          float* out) {
  int t = blockIdx.x * blockDim.x + threadIdx.x;
  if (t >= NB * 256) return;
  out[t] = r0[t] + r1[t];
}

extern "C" __attribute__((visibility("default")))
void kernel_launch(void* const* d_in, const int* in_sizes, int n_in,
                   void* d_out, int out_size, void* d_ws, size_t ws_size,
                   hipStream_t stream) {
  (void)hipGetLastError();

  const float* x = (const float*)d_in[0];
  const float* edge_attr = (const float*)d_in[1];
  const int* edge_index = (const int*)d_in[2];
  const float* edge_weight = (const float*)d_in[3];
  const float* lin0_w = (const float*)d_in[5];
  const float* lin0_b = (const float*)d_in[6];
  const float* lin_w = (const float*)d_in[7];
  const float* lin_b = (const float*)d_in[8];
  const float* q_w = (const float*)d_in[9];
  const float* q_b = (const float*)d_in[10];
  const float* k_w = (const float*)d_in[11];
  const float* k_b = (const float*)d_in[12];
  const float* v_w = (const float*)d_in[13];
  const float* v_b = (const float*)d_in[14];
  const float* e_w = (const float*)d_in[15];
  const float* e_b = (const float*)d_in[16];
  const float* s_w = (const float*)d_in[17];
  const float* s_b = (const float*)d_in[18];
  const float* tr_w = (const float*)d_in[19];
  const float* tr_b = (const float*)d_in[20];
  const float* bn_g = (const float*)d_in[21];
  const float* bn_b = (const float*)d_in[22];
  const float* pool_w = (const float*)d_in[23];
  (void)in_sizes; (void)n_in;

  float* out = (float*)d_out;

  size_t off = 0;
  auto alloc = [&](size_t bytes) -> void* {
    void* r = (char*)d_ws + off;
    off += (bytes + 255) & ~(size_t)255;
    return r;
  };
  float* P0 = (float*)alloc((size_t)NNODES * 128 * 4);
  float* P1 = (float*)alloc((size_t)NNODES * 128 * 4);
  float* XL = (float*)alloc((size_t)NNODES * 128 * 4);
  float* U = (float*)alloc((size_t)NNODES * 512 * 4);  // becomes Z after light pass
  float* G = (float*)alloc((size_t)NNODES * 256 * 4);  // becomes WS after light pass
  float* XW = (float*)alloc((size_t)NNODES * 128 * 4);
  float* DEN = (float*)alloc((size_t)NNODES * 4 * 4);
  float* ATTN = (float*)alloc((size_t)CH * 512 * 4);
  float* SCV = (float*)alloc((size_t)NNODES * 8 * 4);
  _Float16* CtT = (_Float16*)alloc((size_t)2 * 512 * 128 * 2);
  _Float16* BtT = (_Float16*)alloc((size_t)2 * 256 * 128 * 2);
  _Float16* lwT = (_Float16*)alloc((size_t)2 * 128 * 256 * 2);
  _Float16* WvT = (_Float16*)alloc((size_t)2 * 512 * 128 * 2);
  _Float16* EWmT = (_Float16*)alloc((size_t)2 * 512 * 64 * 2);
  _Float16* SwT = (_Float16*)alloc((size_t)2 * 512 * 128 * 2);
  _Float16* TrT = (_Float16*)alloc((size_t)2 * 128 * 512 * 2);
  float* GB = (float*)alloc(256 * 4);
  float* WCR = (float*)alloc(128 * 8 * 4);
  float* CC = (float*)alloc(4 * 4);
  float* DIS = (float*)alloc((size_t)NNODES * 4);
  int* EI0 = (int*)alloc((size_t)NEDGES * 4);
  int* EI1 = (int*)alloc((size_t)NEDGES * 4);
  float* EWF = (float*)alloc((size_t)NEDGES * 4);
  int* EMASK = (int*)alloc((size_t)NEDGES * 4);
  int* CNT = (int*)alloc((size_t)NNODES * 4);
  int* INDPTR = (int*)alloc((size_t)(NNODES + 256) * 4);
  int* CURSOR = (int*)alloc((size_t)NNODES * 4);
  int4* PCK4 = (int4*)alloc((size_t)NEDGES * 16);
  int* TOFF = (int*)alloc((size_t)(NNODES / 4) * 4);
  int* BSUM = (int*)alloc((size_t)64 * 4);
  int* BOFF = (int*)alloc((size_t)64 * 4);
  float* SCORE = (float*)alloc((size_t)NNODES * 4);
  int* NEWID = (int*)alloc((size_t)NNODES * 4);
  int* SELI = (int*)alloc((size_t)16384 * 4);
  float* GATEV = (float*)alloc((size_t)16384 * 4);
  float* REPS0 = (float*)alloc((size_t)NB * 256 * 4);
  float* REPS1 = (float*)alloc((size_t)NB * 256 * 4);
  float* RPART = (float*)alloc((size_t)NB * RSPLIT * 256 * 4);
  float* PART1 = (float*)alloc((size_t)256 * 128 * 4);
  float* PART2 = (float*)alloc((size_t)256 * 128 * 4);
  float* MU = (float*)alloc(128 * 4);
  float* RSTD = (float*)alloc(128 * 4);
  float* WN = (float*)alloc(256);
  const int ws_ok = (ws_size >= off) ? 1 : 0;

  edge_init<<<NEDGES / 256, 256, 0, stream>>>(edge_index, edge_weight, EI0, EI1, EWF, EMASK);
  if (hipGetLastError() != hipSuccess) {
    stream = (hipStream_t)0;
    edge_init<<<NEDGES / 256, 256, 0, stream>>>(edge_index, edge_weight, EI0, EI1, EWF, EMASK);
    (void)hipGetLastError();
  }

  if (!ws_ok) {
    fill_f32<<<(out_size + 255) / 256, 256, 0, stream>>>(out, 3000.f, out_size);
    return;
  }

  // Build CSR + degree norm for the current edge set (only changes at pools).
  auto build_graph = [&](int n) {
    fill_dc<<<(n + 255) / 256, 256, 0, stream>>>(DIS, CNT, n);
    deg_cnt<<<NEDGES / 256, 256, 0, stream>>>(EI0, EI1, EMASK, DIS, CNT);
    scan_p1<<<n / 1024, 256, 0, stream>>>(CNT, DIS, TOFF, BSUM);
    scan_p2<<<1, 64, 0, stream>>>(BSUM, BOFF, n / 1024, INDPTR, n);
    scan_p3<<<n / 1024, 256, 0, stream>>>(CNT, TOFF, BOFF, INDPTR, CURSOR);
    csr_fill<<<NEDGES / 256, 256, 0, stream>>>(EI0, EI1, EMASK, EWF, DIS, CURSOR, PCK4);
  };

  auto conv = [&](int n, const float* Ain, int K0, float* Pout, const float* lw,
                  const float* lb, int l) {
    const float* qwl = q_w + (size_t)l * 128 * 512;
    const float* qbl = q_b + (size_t)l * 512;
    const float* kwl = k_w + (size_t)l * 128 * 512;
    const float* kbl = k_b + (size_t)l * 512;
    const float* vwl = v_w + (size_t)l * 128 * 512;
    const float* vbl = v_b + (size_t)l * 512;
    const float* ewl = e_w + (size_t)l * 64 * 512;
    const float* ebl = e_b + (size_t)l * 512;
    const float* swl = s_w + (size_t)l * 128 * 512;
    const float* sbl = s_b + (size_t)l * 512;
    const float* trwl = tr_w + (size_t)l * 512 * 128;
    const float* trbl = tr_b + (size_t)l * 128;

    prep_all<<<388, 256, 0, stream>>>(qwl, kwl, ewl, qbl, kbl, ebl, CtT, BtT, GB, WCR, CC);
    const int wtot = K0 * 128 + 229376;
    wsplit_all<<<(wtot + 255) / 256, 256, 0, stream>>>(lw, K0, vwl, ewl, swl, trwl,
                                                       lwT, WvT, EWmT, SwT, TrT);

    mgemm<<<dim3(n / 128, 1), 256, 0, stream>>>(Ain, lwT, lb, XL, n, K0, 128, 0);
    mgemm<<<dim3(n / 128, 4), 256, 0, stream>>>(XL, CtT, nullptr, U, n, 128, 512, 0);
    mgemm<<<dim3(n / 128, 2), 256, 0, stream>>>(XL, BtT, GB, G, n, 128, 256, 0);
    node_scalars<<<n / 32, 256, 0, stream>>>(XL, WCR, CC, SCV, n);

    fused_attn_light<<<n / 4, 256, 0, stream>>>(PCK4, INDPTR, edge_attr, XL,
                                                U, G, SCV, DIS, XW, DEN);

    for (int cb = 0; cb < n; cb += CH) {
      mattn<<<dim3(CH / 128, 4), 256, 0, stream>>>(U, G, XL, XW, DEN, WvT, EWmT, SwT,
                                                   vbl, ebl, sbl, ATTN, cb);
      mgemm<<<dim3(CH / 128, 1), 256, 0, stream>>>(ATTN, TrT, trbl,
                                                   Pout + (size_t)cb * 128, CH, 512,
                                                   128, 1);
    }
    bn_accum<<<256, 256, 0, stream>>>(Pout, PART1, PART2, n);
    bn_final<<<1, 128, 0, stream>>>(PART1, PART2, MU, RSTD, n);
    bn_apply<<<(n * 128) / 256, 256, 0, stream>>>(Pout, MU, RSTD, bn_g + l * 128,
                                                  bn_b + l * 128, n);
  };

  auto pool = [&](int pi, const float* hSrc, float* hDst, int nOld, int M, float* reps) {
    wnorm_kernel<<<1, 128, 0, stream>>>(pool_w + pi * 128, WN);
    score_kernel<<<(nOld + 255) / 256, 256, 0, stream>>>(hSrc, pool_w + pi * 128, WN,
                                                         SCORE, nOld);
    fill_i32<<<(nOld + 255) / 256, 256, 0, stream>>>(NEWID, -1, nOld);
    topk_kernel<<<NB, 512, 0, stream>>>(SCORE, GATEV, SELI, NEWID, M);
    int nNew = nOld / 2;
    gate_kernel<<<(nNew * 128) / 256, 256, 0, stream>>>(hSrc, GATEV, SELI, hDst, nNew);
    relabel_kernel<<<NEDGES / 256, 256, 0, stream>>>(EI0, EI1, EWF, EMASK, NEWID);
    reps_partial<<<NB * RSPLIT, 128, 0, stream>>>(hDst, RPART, M / 2);
    reps_final<<<NB, 128, 0, stream>>>(RPART, reps, M / 2);
  };

  build_graph(NNODES);
  conv(NNODES, x, 256, P0, lin0_w, lin0_b, 0);
  conv(NNODES, P0, 128, P1, lin_w, lin_b, 1);
  pool(0, P1, P0, NNODES, 1024, REPS0);
  build_graph(16384);
  conv(16384, P0, 128, P1, lin_w + 128 * 128, lin_b + 128, 2);
  conv(16384, P1, 128, P0, lin_w + 2 * 128 * 128, lin_b + 2 * 128, 3);
  pool(1, P0, P1, 16384, 512, REPS1);

  final_out<<<NB * 256 / 256, 256, 0, stream>>>(REPS0, REPS1, out);

  if (hipGetLastError() != hipSuccess) {
    hipMemsetAsync(d_out, 0x45, (size_t)out_size * 4, stream);
  }
}

// Round 7
// 1613.484 us; speedup vs baseline: 1.0012x; 1.0012x over previous
//
#include <hip/hip_runtime.h>
#include <math.h>
#include <cstddef>

#define NNODES 32768
#define NEDGES 262144
#define NB 32
#define CH 8192  // epilogue chunk rows
#define RSPLIT 16

typedef _Float16 f16x4 __attribute__((ext_vector_type(4)));
typedef _Float16 f16x8 __attribute__((ext_vector_type(8)));
typedef float f32x4 __attribute__((ext_vector_type(4)));

__device__ __forceinline__ void load8f(const float* p, float* o) {
  float4 a = *reinterpret_cast<const float4*>(p);
  float4 b = *reinterpret_cast<const float4*>(p + 4);
  o[0] = a.x; o[1] = a.y; o[2] = a.z; o[3] = a.w;
  o[4] = b.x; o[5] = b.y; o[6] = b.z; o[7] = b.w;
}

__global__ void GraphEncoder_82575041233261_kernel() {}

__global__ void fill_f32(float* p, float v, int n) {
  int i = blockIdx.x * blockDim.x + threadIdx.x;
  if (i < n) p[i] = v;
}
__global__ void fill_i32(int* p, int v, int n) {
  int i = blockIdx.x * blockDim.x + threadIdx.x;
  if (i < n) p[i] = v;
}
__global__ void fill_dc(float* dis, int* cnt, int n) {
  int i = blockIdx.x * blockDim.x + threadIdx.x;
  if (i < n) { dis[i] = 0.f; cnt[i] = 0; }
}

__global__ void edge_init(const int* __restrict__ ei, const float* __restrict__ ew,
                          int* ei0, int* ei1, float* ewf, int* emask) {
  int e = blockIdx.x * blockDim.x + threadIdx.x;
  if (e >= NEDGES) return;
  ei0[e] = ei[e];
  ei1[e] = ei[NEDGES + e];
  ewf[e] = ew[e];
  emask[e] = 1;
}

// ================= split-f16 MFMA GEMM machinery =================
struct MTile {
  _Float16 Ah[128][40];
  _Float16 Al[128][40];
  _Float16 Bh[128][40];
  _Float16 Bl[128][40];
};

__device__ __forceinline__ void stageA(MTile& sm, const float* __restrict__ A,
                                       int lda, int tid) {
#pragma unroll
  for (int i = 0; i < 4; i++) {
    int flat = tid + i * 256;            // 1024 float4 = 128 rows x 32 k
    int r = flat >> 3, c4 = (flat & 7) << 2;
    float4 v = *reinterpret_cast<const float4*>(A + (size_t)r * lda + c4);
    _Float16 h0 = (_Float16)v.x, h1 = (_Float16)v.y;
    _Float16 h2 = (_Float16)v.z, h3 = (_Float16)v.w;
    f16x4 hv = {h0, h1, h2, h3};
    f16x4 lv = {(_Float16)(v.x - (float)h0), (_Float16)(v.y - (float)h1),
                (_Float16)(v.z - (float)h2), (_Float16)(v.w - (float)h3)};
    *reinterpret_cast<f16x4*>(&sm.Ah[r][c4]) = hv;
    *reinterpret_cast<f16x4*>(&sm.Al[r][c4]) = lv;
  }
}

__device__ __forceinline__ void stageB(MTile& sm, const _Float16* __restrict__ th,
                                       const _Float16* __restrict__ tl, int Kw,
                                       int tid) {
#pragma unroll
  for (int i = 0; i < 4; i++) {
    int flat = tid + i * 256;            // 1024 chunks of 8 halfs (hi then lo)
    int sel = flat >> 9;                 // uniform per i
    int cc = (flat >> 2) & 127, kc = (flat & 3) << 3;
    const _Float16* s = (sel ? tl : th) + (size_t)cc * Kw + kc;
    f16x8 v = *reinterpret_cast<const f16x8*>(s);
    if (sel)
      *reinterpret_cast<f16x8*>(&sm.Bl[cc][kc]) = v;
    else
      *reinterpret_cast<f16x8*>(&sm.Bh[cc][kc]) = v;
  }
}

__device__ __forceinline__ void mcompute(MTile& sm, f32x4 acc[4][4], int wm,
                                         int wn, int fr, int fq) {
  f16x8 ah[4], al[4], bh[4], bl[4];
#pragma unroll
  for (int m = 0; m < 4; m++) {
    ah[m] = *reinterpret_cast<const f16x8*>(&sm.Ah[wm + m * 16 + fr][fq * 8]);
    al[m] = *reinterpret_cast<const f16x8*>(&sm.Al[wm + m * 16 + fr][fq * 8]);
  }
#pragma unroll
  for (int nn = 0; nn < 4; nn++) {
    bh[nn] = *reinterpret_cast<const f16x8*>(&sm.Bh[wn + nn * 16 + fr][fq * 8]);
    bl[nn] = *reinterpret_cast<const f16x8*>(&sm.Bl[wn + nn * 16 + fr][fq * 8]);
  }
#pragma unroll
  for (int m = 0; m < 4; m++)
#pragma unroll
    for (int nn = 0; nn < 4; nn++) {
      acc[m][nn] = __builtin_amdgcn_mfma_f32_16x16x32_f16(ah[m], bh[nn], acc[m][nn], 0, 0, 0);
      acc[m][nn] = __builtin_amdgcn_mfma_f32_16x16x32_f16(ah[m], bl[nn], acc[m][nn], 0, 0, 0);
      acc[m][nn] = __builtin_amdgcn_mfma_f32_16x16x32_f16(al[m], bh[nn], acc[m][nn], 0, 0, 0);
    }
}

// C[n,M] = A[n,K] @ W + bias (relu optional). W pre-split transposed WT[2][M][K].
__global__ __launch_bounds__(256) void mgemm(
    const float* __restrict__ A, const _Float16* __restrict__ WT,
    const float* __restrict__ bias, float* __restrict__ C,
    int n, int K, int M, int relu) {
  __shared__ MTile sm;
  const int tid = threadIdx.x;
  const int lane = tid & 63, w = tid >> 6;
  const int wm = (w >> 1) << 6, wn = (w & 1) << 6;
  const int fr = lane & 15, fq = lane >> 4;
  const int row0 = blockIdx.x * 128, col0 = blockIdx.y * 128;
  const _Float16* th = WT + (size_t)col0 * K;
  const _Float16* tl = WT + (size_t)M * K + (size_t)col0 * K;
  const float* Ab = A + (size_t)row0 * K;
  f32x4 acc[4][4];
#pragma unroll
  for (int m = 0; m < 4; m++)
#pragma unroll
    for (int nn = 0; nn < 4; nn++) acc[m][nn] = (f32x4){0.f, 0.f, 0.f, 0.f};
  for (int kt = 0; kt < K; kt += 32) {
    stageA(sm, Ab + kt, K, tid);
    stageB(sm, th + kt, tl + kt, K, tid);
    __syncthreads();
    mcompute(sm, acc, wm, wn, fr, fq);
    __syncthreads();
  }
#pragma unroll
  for (int nn = 0; nn < 4; nn++) {
    const int col = col0 + wn + nn * 16 + fr;
    const float b = bias ? bias[col] : 0.f;
#pragma unroll
    for (int m = 0; m < 4; m++)
#pragma unroll
      for (int j = 0; j < 4; j++) {
        int row = row0 + wm + m * 16 + fq * 4 + j;
        float v = acc[m][nn][j] + b;
        if (relu) v = fmaxf(v, 0.f);
        C[(size_t)row * M + col] = v;
      }
  }
}

// attn epilogue GEMM, MFMA version. BN=128 = one head per col-block.
__global__ __launch_bounds__(256) void mattn(
    const float* __restrict__ Z, const float* __restrict__ WS,
    const float* __restrict__ XLv, const float* __restrict__ XW,
    const float* __restrict__ DEN, const _Float16* __restrict__ WvT,
    const _Float16* __restrict__ EWmT, const _Float16* __restrict__ SwT,
    const float* __restrict__ vb, const float* __restrict__ eb,
    const float* __restrict__ sb, float* __restrict__ ATTN, int rowBase) {
  __shared__ MTile sm;
  const int tid = threadIdx.x;
  const int lane = tid & 63, w = tid >> 6;
  const int wm = (w >> 1) << 6, wn = (w & 1) << 6;
  const int fr = lane & 15, fq = lane >> 4;
  const int h = blockIdx.y;
  const int col0 = h << 7;
  const int rloc0 = blockIdx.x * 128;
  const int row0 = rowBase + rloc0;
  f32x4 acc[4][4];
#pragma unroll
  for (int m = 0; m < 4; m++)
#pragma unroll
    for (int nn = 0; nn < 4; nn++) acc[m][nn] = (f32x4){0.f, 0.f, 0.f, 0.f};
  // phase A: K=128 over Z (head slice)
  {
    const float* Ab = Z + (size_t)row0 * 512 + col0;
    const _Float16* th = WvT + (size_t)col0 * 128;
    const _Float16* tl = WvT + (size_t)512 * 128 + (size_t)col0 * 128;
    for (int kt = 0; kt < 128; kt += 32) {
      stageA(sm, Ab + kt, 512, tid);
      stageB(sm, th + kt, tl + kt, 128, tid);
      __syncthreads();
      mcompute(sm, acc, wm, wn, fr, fq);
      __syncthreads();
    }
  }
  // phase B: K=64 over WS (head slice)
  {
    const float* Ab = WS + (size_t)row0 * 256 + (h << 6);
    const _Float16* th = EWmT + (size_t)col0 * 64;
    const _Float16* tl = EWmT + (size_t)512 * 64 + (size_t)col0 * 64;
    for (int kt = 0; kt < 64; kt += 32) {
      stageA(sm, Ab + kt, 256, tid);
      stageB(sm, th + kt, tl + kt, 64, tid);
      __syncthreads();
      mcompute(sm, acc, wm, wn, fr, fq);
      __syncthreads();
    }
  }
  // mid: den scaling + biases
  {
    float vbe[4], sbv[4];
#pragma unroll
    for (int nn = 0; nn < 4; nn++) {
      int col = col0 + wn + nn * 16 + fr;
      vbe[nn] = vb[col] + eb[col];
      sbv[nn] = sb[col];
    }
#pragma unroll
    for (int m = 0; m < 4; m++)
#pragma unroll
      for (int j = 0; j < 4; j++) {
        int row = row0 + wm + m * 16 + fq * 4 + j;
        float d = DEN[(size_t)row * 4 + h];
        float inv = 1.f / (d + 1e-16f);
#pragma unroll
        for (int nn = 0; nn < 4; nn++)
          acc[m][nn][j] = (acc[m][nn][j] + d * vbe[nn]) * inv + sbv[nn];
      }
  }
  // phase C: K=128 over XL (skip branch), accumulates post-scaling
  {
    const float* Ab = XLv + (size_t)row0 * 128;
    const _Float16* th = SwT + (size_t)col0 * 128;
    const _Float16* tl = SwT + (size_t)512 * 128 + (size_t)col0 * 128;
    for (int kt = 0; kt < 128; kt += 32) {
      stageA(sm, Ab + kt, 128, tid);
      stageB(sm, th + kt, tl + kt, 128, tid);
      __syncthreads();
      mcompute(sm, acc, wm, wn, fr, fq);
      __syncthreads();
    }
  }
#pragma unroll
  for (int nn = 0; nn < 4; nn++) {
    int col = col0 + wn + nn * 16 + fr;
#pragma unroll
    for (int m = 0; m < 4; m++)
#pragma unroll
      for (int j = 0; j < 4; j++) {
        int rl = rloc0 + wm + m * 16 + fq * 4 + j;
        float v = acc[m][nn][j] + XW[(size_t)(rowBase + rl) * 128 + (col & 127)];
        ATTN[(size_t)rl * 512 + col] = v;
      }
  }
}

// ---- merged weight prep: split fp32 W[K][M] -> WT[2][M][K] f16 for all 5 ----
__global__ void wsplit_all(const float* __restrict__ lw, int K0,
                           const float* __restrict__ vw, const float* __restrict__ ew,
                           const float* __restrict__ sw, const float* __restrict__ trw,
                           _Float16* __restrict__ lwT, _Float16* __restrict__ WvT,
                           _Float16* __restrict__ EWmT, _Float16* __restrict__ SwT,
                           _Float16* __restrict__ TrT) {
  int idx = blockIdx.x * 256 + threadIdx.x;
  const float* W; _Float16* T; int K, msh, loc;
  const int s0 = K0 << 7;
  if (idx < s0) { W = lw; T = lwT; K = K0; msh = 7; loc = idx; }
  else if (idx < s0 + 65536) { W = vw; T = WvT; K = 128; msh = 9; loc = idx - s0; }
  else if (idx < s0 + 98304) { W = ew; T = EWmT; K = 64; msh = 9; loc = idx - s0 - 65536; }
  else if (idx < s0 + 163840) { W = sw; T = SwT; K = 128; msh = 9; loc = idx - s0 - 98304; }
  else if (idx < s0 + 229376) { W = trw; T = TrT; K = 512; msh = 7; loc = idx - s0 - 163840; }
  else return;
  int M = 1 << msh;
  int k = loc >> msh, m2 = loc & (M - 1);
  float v = W[loc];
  _Float16 hh = (_Float16)v;
  T[(size_t)m2 * K + k] = hh;
  T[(size_t)M * K + (size_t)m2 * K + k] = (_Float16)(v - (float)hh);
}

// ---- merged folded-weight prep (float4-vectorized inner loops) ----
__global__ __launch_bounds__(256) void prep_all(
    const float* __restrict__ Wq, const float* __restrict__ Wk,
    const float* __restrict__ EWm, const float* __restrict__ bq,
    const float* __restrict__ bk, const float* __restrict__ eb,
    _Float16* __restrict__ CtT, _Float16* __restrict__ BtT,
    float* __restrict__ gb, float* __restrict__ WCR, float* __restrict__ CC) {
  int idx = blockIdx.x * 256 + threadIdx.x;
  if (idx < 65536) {
    int cin = idx >> 9, r = idx & 511, h = r >> 7, co = r & 127;
    const float4* a4 = reinterpret_cast<const float4*>(Wq + cin * 512 + h * 128);
    const float4* b4 = reinterpret_cast<const float4*>(Wk + co * 512 + h * 128);
    float acc = 0.f;
#pragma unroll 8
    for (int c = 0; c < 32; c++) {
      float4 a = a4[c], b = b4[c];
      acc += a.x * b.x + a.y * b.y + a.z * b.z + a.w * b.w;
    }
    _Float16 hh = (_Float16)acc;
    CtT[(size_t)r * 128 + cin] = hh;
    CtT[(size_t)512 * 128 + (size_t)r * 128 + cin] = (_Float16)(acc - (float)hh);
  } else if (idx < 98304) {
    int t = idx - 65536;
    int cin = t >> 8, r = t & 255, h = r >> 6, f = r & 63;
    const float4* a4 = reinterpret_cast<const float4*>(Wq + cin * 512 + h * 128);
    const float4* b4 = reinterpret_cast<const float4*>(EWm + f * 512 + h * 128);
    float acc = 0.f;
#pragma unroll 8
    for (int c = 0; c < 32; c++) {
      float4 a = a4[c], b = b4[c];
      acc += a.x * b.x + a.y * b.y + a.z * b.z + a.w * b.w;
    }
    _Float16 hh = (_Float16)acc;
    BtT[(size_t)r * 128 + cin] = hh;
    BtT[(size_t)256 * 128 + (size_t)r * 128 + cin] = (_Float16)(acc - (float)hh);
    if (cin == 0) {
      const float4* c4 = reinterpret_cast<const float4*>(bq + h * 128);
      float s = 0.f;
#pragma unroll 8
      for (int c = 0; c < 32; c++) {
        float4 a = b4[c], b = c4[c];
        s += a.x * b.x + a.y * b.y + a.z * b.z + a.w * b.w;
      }
      gb[r] = s;
    }
  } else if (idx < 99328) {
    int tid = idx - 98304;
    int cin = tid >> 3, j = tid & 7, h2 = j & 3, isR = j >> 2;
    float acc = 0.f;
    if (isR) {
      for (int c = 0; c < 128; c++)
        acc += Wk[cin * 512 + h2 * 128 + c] * bq[h2 * 128 + c];
    } else {
      for (int c = 0; c < 128; c++)
        acc += Wq[cin * 512 + h2 * 128 + c] * (bk[h2 * 128 + c] + eb[h2 * 128 + c]);
    }
    WCR[cin * 8 + j] = acc;
    if (tid < 4) {
      float s = 0.f;
      for (int c = 0; c < 128; c++)
        s += bq[tid * 128 + c] * (bk[tid * 128 + c] + eb[tid * 128 + c]);
      CC[tid] = s;
    }
  }
}

// SCV[node, j] = XL[node]·WCR[:,j] (+CC for j<4); float4 loads
__global__ __launch_bounds__(256) void node_scalars(const float* __restrict__ XL,
                                                    const float* __restrict__ WCR,
                                                    const float* __restrict__ CC,
                                                    float* __restrict__ SCV, int n) {
  int t = blockIdx.x * 256 + threadIdx.x;
  if (t >= n * 8) return;
  int node = t >> 3, j = t & 7;
  const float4* x4 = reinterpret_cast<const float4*>(XL + (size_t)node * 128);
  float acc = (j < 4) ? CC[j] : 0.f;
#pragma unroll 8
  for (int c = 0; c < 32; c++) {
    float4 v = x4[c];
    acc += v.x * WCR[(c * 4) * 8 + j] + v.y * WCR[(c * 4 + 1) * 8 + j] +
           v.z * WCR[(c * 4 + 2) * 8 + j] + v.w * WCR[(c * 4 + 3) * 8 + j];
  }
  SCV[t] = acc;
}

// merged degree + indegree count
__global__ void deg_cnt(const int* __restrict__ ei0, const int* __restrict__ ei1,
                        const int* __restrict__ emask, float* deg, int* cnt) {
  int e = blockIdx.x * blockDim.x + threadIdx.x;
  if (e >= NEDGES) return;
  if (emask[e]) {
    atomicAdd(&deg[ei0[e]], 1.0f);
    atomicAdd(&cnt[ei1[e]], 1);
  }
}

// ---- parallel 3-phase exclusive scan over cnt (n multiple of 1024) ----
__global__ __launch_bounds__(256) void scan_p1(const int* __restrict__ cnt,
                                               float* __restrict__ dis,
                                               int* __restrict__ toff,
                                               int* __restrict__ bsum) {
  const int b = blockIdx.x, tid = threadIdx.x;
  const int gi = b * 1024 + tid * 4;
  int4 c = *reinterpret_cast<const int4*>(cnt + gi);
  float4 d = *reinterpret_cast<const float4*>(dis + gi);
  float4 dr;
  dr.x = d.x > 0.f ? rsqrtf(d.x) : 0.f;
  dr.y = d.y > 0.f ? rsqrtf(d.y) : 0.f;
  dr.z = d.z > 0.f ? rsqrtf(d.z) : 0.f;
  dr.w = d.w > 0.f ? rsqrtf(d.w) : 0.f;
  *reinterpret_cast<float4*>(dis + gi) = dr;
  int s = c.x + c.y + c.z + c.w;
  __shared__ int sh[256];
  sh[tid] = s;
  __syncthreads();
  for (int dstep = 1; dstep < 256; dstep <<= 1) {
    int t = (tid >= dstep) ? sh[tid - dstep] : 0;
    __syncthreads();
    sh[tid] += t;
    __syncthreads();
  }
  toff[b * 256 + tid] = sh[tid] - s;  // exclusive within block
  if (tid == 255) bsum[b] = sh[255];
}
__global__ void scan_p2(const int* __restrict__ bsum, int* __restrict__ boff,
                        int nb, int* __restrict__ indptr, int n) {
  if (threadIdx.x == 0) {
    int run = 0;
    for (int i = 0; i < nb; i++) { boff[i] = run; run += bsum[i]; }
    indptr[n] = run;
  }
}
__global__ __launch_bounds__(256) void scan_p3(const int* __restrict__ cnt,
                                               const int* __restrict__ toff,
                                               const int* __restrict__ boff,
                                               int* __restrict__ indptr,
                                               int* __restrict__ cursor) {
  const int b = blockIdx.x, tid = threadIdx.x;
  const int gi = b * 1024 + tid * 4;
  int4 c = *reinterpret_cast<const int4*>(cnt + gi);
  int run = boff[b] + toff[b * 256 + tid];
  int4 o;
  o.x = run;
  o.y = run + c.x;
  o.z = o.y + c.y;
  o.w = o.z + c.z;
  *reinterpret_cast<int4*>(indptr + gi) = o;
  *reinterpret_cast<int4*>(cursor + gi) = o;
}

// CSR fill, packed 16B records: PCK[p]={src, e, bits(dis[src]*ewf[e]), 0}
__global__ void csr_fill(const int* __restrict__ ei0, const int* __restrict__ ei1,
                         const int* __restrict__ emask, const float* __restrict__ ewf,
                         const float* __restrict__ dis, int* cursor,
                         int4* __restrict__ pck) {
  int e = blockIdx.x * blockDim.x + threadIdx.x;
  if (e >= NEDGES) return;
  if (!emask[e]) return;
  int p = atomicAdd(&cursor[ei1[e]], 1);
  int r = ei0[e];
  int4 rec;
  rec.x = r;
  rec.y = e;
  rec.z = __float_as_int(dis[r] * ewf[e]);
  rec.w = 0;
  pck[p] = rec;
}

// ---- light attention pass: ONE NODE PER 256-THREAD BLOCK, 4 waves split the
// edge list (wave w takes edges beg+w, beg+w+4, ...). Each wave runs the cheap
// defer-max online softmax on its quarter; partial states merged exactly via
// LDS (m'=max, scale by e^{m_w-m'}). Serial chain per wave: ~2 edges instead
// of ~8; 4x the wave-level parallelism at round-4 register cost.
__global__ __launch_bounds__(256) void fused_attn_light(
    const int4* __restrict__ PCK, const int* __restrict__ indptr,
    const float* __restrict__ EA, const float* __restrict__ XLv,
    float* U, float* G, const float* __restrict__ SCVv,
    const float* __restrict__ DISv, float* __restrict__ XW,
    float* __restrict__ DEN) {
  __shared__ float sZ[4][64][8];
  __shared__ float sW[4][64][4];
  __shared__ float sXW[4][16][8];
  __shared__ float sMD[4][4][2];
  const int w = threadIdx.x >> 6, lane = threadIdx.x & 63;
  const int h = lane >> 4, t16 = lane & 15;
  const int col = blockIdx.x;
  float u8[8];
  load8f(U + (size_t)col * 512 + lane * 8, u8);
  float4 g4 = *reinterpret_cast<const float4*>(G + (size_t)col * 256 + lane * 4);
  const float colS = SCVv[col * 8 + h];
  const int beg = indptr[col], end = indptr[col + 1];
  const float rs = 0.08838834764831845f;  // 1/sqrt(128)
  float m = -3.0e38f, den = 0.f;
  float z8[8] = {0.f, 0.f, 0.f, 0.f, 0.f, 0.f, 0.f, 0.f};
  float w4[4] = {0.f, 0.f, 0.f, 0.f};
  float xw8[8] = {0.f, 0.f, 0.f, 0.f, 0.f, 0.f, 0.f, 0.f};
  for (int i = beg + w; i < end; i += 4) {
    const int4 rec = PCK[i];
    const float dn = __int_as_float(rec.z);
    const float rowS = SCVv[(size_t)rec.x * 8 + 4 + h];
    float xr[8];
    load8f(XLv + (size_t)rec.x * 128 + t16 * 8, xr);
    float4 ea4 = *reinterpret_cast<const float4*>(EA + (size_t)rec.y * 64 + t16 * 4);
    float pa = 0.f;
#pragma unroll
    for (int j = 0; j < 8; j++) pa += u8[j] * xr[j];
    pa += g4.x * ea4.x + g4.y * ea4.y + g4.z * ea4.z + g4.w * ea4.w;
    pa += __shfl_xor(pa, 1);
    pa += __shfl_xor(pa, 2);
    pa += __shfl_xor(pa, 4);
    pa += __shfl_xor(pa, 8);
    const float alpha = (pa + colS + rowS) * rs;
    if (alpha > m + 8.f) {  // rare rescale (P bounded by e^8 between rescales)
      const float sc = __expf(m - alpha);
      den *= sc;
#pragma unroll
      for (int j = 0; j < 8; j++) z8[j] *= sc;
      w4[0] *= sc; w4[1] *= sc; w4[2] *= sc; w4[3] *= sc;
      m = alpha;
    }
    const float a = __expf(alpha - m);
    den += a;
#pragma unroll
    for (int j = 0; j < 8; j++) z8[j] += a * xr[j];
    w4[0] += a * ea4.x;
    w4[1] += a * ea4.y;
    w4[2] += a * ea4.z;
    w4[3] += a * ea4.w;
#pragma unroll
    for (int j = 0; j < 8; j++) xw8[j] += dn * xr[j];
  }
  // stash partial state
  if (t16 == 0) { sMD[w][h][0] = m; sMD[w][h][1] = den; }
#pragma unroll
  for (int j = 0; j < 8; j++) sZ[w][lane][j] = z8[j];
#pragma unroll
  for (int j = 0; j < 4; j++) sW[w][lane][j] = w4[j];
  if (h == 0) {
#pragma unroll
    for (int j = 0; j < 8; j++) sXW[w][t16][j] = xw8[j];
  }
  __syncthreads();
  if (w != 0) return;
  // exact merge of 4 partial online-softmax states (wave 0 only)
  const float m0 = sMD[0][h][0], m1 = sMD[1][h][0];
  const float m2 = sMD[2][h][0], m3 = sMD[3][h][0];
  const float mm = fmaxf(fmaxf(m0, m1), fmaxf(m2, m3));
  const float s0 = __expf(m0 - mm), s1 = __expf(m1 - mm);
  const float s2 = __expf(m2 - mm), s3 = __expf(m3 - mm);
  const float dsum = sMD[0][h][1] * s0 + sMD[1][h][1] * s1 +
                     sMD[2][h][1] * s2 + sMD[3][h][1] * s3;
  float zf[8], wf[4];
#pragma unroll
  for (int j = 0; j < 8; j++)
    zf[j] = sZ[0][lane][j] * s0 + sZ[1][lane][j] * s1 +
            sZ[2][lane][j] * s2 + sZ[3][lane][j] * s3;
#pragma unroll
  for (int j = 0; j < 4; j++)
    wf[j] = sW[0][lane][j] * s0 + sW[1][lane][j] * s1 +
            sW[2][lane][j] * s2 + sW[3][lane][j] * s3;
  float4 o1, o2;
  o1.x = zf[0]; o1.y = zf[1]; o1.z = zf[2]; o1.w = zf[3];
  o2.x = zf[4]; o2.y = zf[5]; o2.z = zf[6]; o2.w = zf[7];
  *reinterpret_cast<float4*>(U + (size_t)col * 512 + lane * 8) = o1;
  *reinterpret_cast<float4*>(U + (size_t)col * 512 + lane * 8 + 4) = o2;
  float4 ow;
  ow.x = wf[0]; ow.y = wf[1]; ow.z = wf[2]; ow.w = wf[3];
  *reinterpret_cast<float4*>(G + (size_t)col * 256 + lane * 4) = ow;
  if (h == 0) {  // degree-norm branch (xw partials just add)
    const float dcol = DISv[col];
    float4 x1, x2;
    x1.x = (sXW[0][t16][0] + sXW[1][t16][0] + sXW[2][t16][0] + sXW[3][t16][0]) * dcol;
    x1.y = (sXW[0][t16][1] + sXW[1][t16][1] + sXW[2][t16][1] + sXW[3][t16][1]) * dcol;
    x1.z = (sXW[0][t16][2] + sXW[1][t16][2] + sXW[2][t16][2] + sXW[3][t16][2]) * dcol;
    x1.w = (sXW[0][t16][3] + sXW[1][t16][3] + sXW[2][t16][3] + sXW[3][t16][3]) * dcol;
    x2.x = (sXW[0][t16][4] + sXW[1][t16][4] + sXW[2][t16][4] + sXW[3][t16][4]) * dcol;
    x2.y = (sXW[0][t16][5] + sXW[1][t16][5] + sXW[2][t16][5] + sXW[3][t16][5]) * dcol;
    x2.z = (sXW[0][t16][6] + sXW[1][t16][6] + sXW[2][t16][6] + sXW[3][t16][6]) * dcol;
    x2.w = (sXW[0][t16][7] + sXW[1][t16][7] + sXW[2][t16][7] + sXW[3][t16][7]) * dcol;
    *reinterpret_cast<float4*>(XW + (size_t)col * 128 + t16 * 8) = x1;
    *reinterpret_cast<float4*>(XW + (size_t)col * 128 + t16 * 8 + 4) = x2;
  }
  if (t16 == 0) DEN[col * 4 + h] = dsum;
}

// ---- batchnorm (in-place) ----
__global__ __launch_bounds__(256) void bn_accum(const float* __restrict__ x,
                                                float* __restrict__ part1,
                                                float* __restrict__ part2, int n) {
  __shared__ float sh1[256], sh2[256];
  int c = threadIdx.x & 127;
  int half = threadIdx.x >> 7;
  float a = 0.f, b = 0.f;
  for (int i = blockIdx.x * 2 + half; i < n; i += gridDim.x * 2) {
    float v = x[(size_t)i * 128 + c];
    a += v;
    b += v * v;
  }
  sh1[threadIdx.x] = a;
  sh2[threadIdx.x] = b;
  __syncthreads();
  if (half == 0) {
    part1[blockIdx.x * 128 + c] = a + sh1[threadIdx.x + 128];
    part2[blockIdx.x * 128 + c] = b + sh2[threadIdx.x + 128];
  }
}
__global__ void bn_final(const float* __restrict__ part1, const float* __restrict__ part2,
                         float* mu, float* rstd, int n) {
  int c = threadIdx.x;
  if (c >= 128) return;
  float s1 = 0.f, s2 = 0.f;
#pragma unroll 8
  for (int b = 0; b < 256; b++) {
    s1 += part1[b * 128 + c];
    s2 += part2[b * 128 + c];
  }
  float m = s1 / (float)n;
  mu[c] = m;
  float var = s2 / (float)n - m * m;
  rstd[c] = rsqrtf(var + 1e-5f);
}
__global__ void bn_apply(float* x, const float* __restrict__ mu,
                         const float* __restrict__ rstd, const float* __restrict__ g,
                         const float* __restrict__ b, int n) {
  int t = blockIdx.x * blockDim.x + threadIdx.x;
  if (t >= n * 128) return;
  int c = t & 127;
  x[t] = g[c] * (x[t] - mu[c]) * rstd[c] + b[c];
}

// ---- pooling ----
__global__ void wnorm_kernel(const float* __restrict__ w, float* wn) {
  __shared__ float s[128];
  int t = threadIdx.x;
  float v = w[t];
  s[t] = v * v;
  __syncthreads();
  for (int st = 64; st > 0; st >>= 1) {
    if (t < st) s[t] += s[t + st];
    __syncthreads();
  }
  if (t == 0) wn[0] = sqrtf(s[0]) + 1e-16f;
}
__global__ void score_kernel(const float* __restrict__ h, const float* __restrict__ w,
                             const float* __restrict__ wn, float* s, int n) {
  int i = blockIdx.x * blockDim.x + threadIdx.x;
  if (i >= n) return;
  const float4* hr = reinterpret_cast<const float4*>(h + (size_t)i * 128);
  const float4* wr = reinterpret_cast<const float4*>(w);
  float d = 0.f;
  for (int c = 0; c < 32; c++) {
    float4 a = hr[c], b = wr[c];
    d += a.x * b.x + a.y * b.y + a.z * b.z + a.w * b.w;
  }
  s[i] = tanhf(d / wn[0]);
}
__global__ __launch_bounds__(512) void topk_kernel(const float* __restrict__ s,
                                                   float* gateVal, int* selIdx,
                                                   int* newid, int M) {
  __shared__ float sv[1024];
  __shared__ int si[1024];
  const int g = blockIdx.x;
  const int k = M >> 1;
  for (int t = threadIdx.x; t < 1024; t += 512) {
    if (t < M) {
      sv[t] = s[(size_t)g * M + t];
      si[t] = t;
    } else {
      sv[t] = -3.4e38f;
      si[t] = 0x7fffffff;
    }
  }
  __syncthreads();
  for (int kk = 2; kk <= 1024; kk <<= 1) {
    for (int j = kk >> 1; j > 0; j >>= 1) {
      for (int t = threadIdx.x; t < 1024; t += 512) {
        int p = t ^ j;
        if (p > t) {
          float va = sv[t], vb2 = sv[p];
          int ia = si[t], ib = si[p];
          bool beforeBA = (vb2 > va) || (vb2 == va && ib < ia);
          bool beforeAB = (va > vb2) || (va == vb2 && ia < ib);
          bool dir = ((t & kk) == 0);
          bool sw = dir ? beforeBA : beforeAB;
          if (sw) {
            sv[t] = vb2;
            sv[p] = va;
            si[t] = ib;
            si[p] = ia;
          }
        }
      }
      __syncthreads();
    }
  }
  for (int j = threadIdx.x; j < k; j += 512) {
    int oldg = g * M + si[j];
    int newg = g * k + j;
    gateVal[newg] = sv[j];
    selIdx[newg] = oldg;
    newid[oldg] = newg;
  }
}
__global__ void gate_kernel(const float* __restrict__ hOld, const float* __restrict__ gv,
                            const int* __restrict__ sel, float* __restrict__ hNew,
                            int nNew) {
  int t = blockIdx.x * blockDim.x + threadIdx.x;
  if (t >= nNew * 128) return;
  int i = t >> 7, c = t & 127;
  hNew[t] = hOld[(size_t)sel[i] * 128 + c] * gv[i];
}
__global__ void relabel_kernel(int* ei0, int* ei1, float* ewf, int* emask,
                               const int* __restrict__ newid) {
  int e = blockIdx.x * blockDim.x + threadIdx.x;
  if (e >= NEDGES) return;
  int nr = newid[ei0[e]];
  int nc = newid[ei1[e]];
  int keep = (nr >= 0 && nc >= 0 && emask[e]) ? 1 : 0;
  ei0[e] = keep ? nr : 0;
  ei1[e] = keep ? nc : 0;
  ewf[e] = keep ? ewf[e] : 0.f;
  emask[e] = keep;
}
// ---- reps: split row-reduction for occupancy ----
__global__ void reps_partial(const float* __restrict__ h, float* __restrict__ rpart,
                             int k) {
  int g = blockIdx.x / RSPLIT, s = blockIdx.x % RSPLIT;
  int c = threadIdx.x;
  int per = k / RSPLIT;
  int j0 = s * per;
  float mx = -3.4e38f, sm = 0.f;
  for (int j = j0; j < j0 + per; j++) {
    float v = h[(size_t)(g * k + j) * 128 + c];
    mx = fmaxf(mx, v);
    sm += v;
  }
  rpart[(size_t)(g * RSPLIT + s) * 256 + c] = mx;
  rpart[(size_t)(g * RSPLIT + s) * 256 + 128 + c] = sm;
}
__global__ void reps_final(const float* __restrict__ rpart, float* __restrict__ rep,
                           int k) {
  int g = blockIdx.x, c = threadIdx.x;
  float mx = -3.4e38f, sm = 0.f;
  for (int s = 0; s < RSPLIT; s++) {
    mx = fmaxf(mx, rpart[(size_t)(g * RSPLIT + s) * 256 + c]);
    sm += rpart[(size_t)(g * RSPLIT + s) * 256 + 128 + c];
  }
  rep[g * 256 + c] = mx;
  rep[g * 256 + 128 + c] = sm / (float)k;
}
__global__ void final_out(const float* __restrict__ r0, const float* __restrict__ r1,
                          float* out) {
  int t = blockIdx.x * blockDim.x + threadIdx.x;
  if (t >= NB * 256) return;
  out[t] = r0[t] + r1[t];
}

extern "C" __attribute__((visibility("default")))
void kernel_launch(void* const* d_in, const int* in_sizes, int n_in,
                   void* d_out, int out_size, void* d_ws, size_t ws_size,
                   hipStream_t stream) {
  (void)hipGetLastError();

  const float* x = (const float*)d_in[0];
  const float* edge_attr = (const float*)d_in[1];
  const int* edge_index = (const int*)d_in[2];
  const float* edge_weight = (const float*)d_in[3];
  const float* lin0_w = (const float*)d_in[5];
  const float* lin0_b = (const float*)d_in[6];
  const float* lin_w = (const float*)d_in[7];
  const float* lin_b = (const float*)d_in[8];
  const float* q_w = (const float*)d_in[9];
  const float* q_b = (const float*)d_in[10];
  const float* k_w = (const float*)d_in[11];
  const float* k_b = (const float*)d_in[12];
  const float* v_w = (const float*)d_in[13];
  const float* v_b = (const float*)d_in[14];
  const float* e_w = (const float*)d_in[15];
  const float* e_b = (const float*)d_in[16];
  const float* s_w = (const float*)d_in[17];
  const float* s_b = (const float*)d_in[18];
  const float* tr_w = (const float*)d_in[19];
  const float* tr_b = (const float*)d_in[20];
  const float* bn_g = (const float*)d_in[21];
  const float* bn_b = (const float*)d_in[22];
  const float* pool_w = (const float*)d_in[23];
  (void)in_sizes; (void)n_in;

  float* out = (float*)d_out;

  size_t off = 0;
  auto alloc = [&](size_t bytes) -> void* {
    void* r = (char*)d_ws + off;
    off += (bytes + 255) & ~(size_t)255;
    return r;
  };
  float* P0 = (float*)alloc((size_t)NNODES * 128 * 4);
  float* P1 = (float*)alloc((size_t)NNODES * 128 * 4);
  float* XL = (float*)alloc((size_t)NNODES * 128 * 4);
  float* U = (float*)alloc((size_t)NNODES * 512 * 4);  // becomes Z after light pass
  float* G = (float*)alloc((size_t)NNODES * 256 * 4);  // becomes WS after light pass
  float* XW = (float*)alloc((size_t)NNODES * 128 * 4);
  float* DEN = (float*)alloc((size_t)NNODES * 4 * 4);
  float* ATTN = (float*)alloc((size_t)CH * 512 * 4);
  float* SCV = (float*)alloc((size_t)NNODES * 8 * 4);
  _Float16* CtT = (_Float16*)alloc((size_t)2 * 512 * 128 * 2);
  _Float16* BtT = (_Float16*)alloc((size_t)2 * 256 * 128 * 2);
  _Float16* lwT = (_Float16*)alloc((size_t)2 * 128 * 256 * 2);
  _Float16* WvT = (_Float16*)alloc((size_t)2 * 512 * 128 * 2);
  _Float16* EWmT = (_Float16*)alloc((size_t)2 * 512 * 64 * 2);
  _Float16* SwT = (_Float16*)alloc((size_t)2 * 512 * 128 * 2);
  _Float16* TrT = (_Float16*)alloc((size_t)2 * 128 * 512 * 2);
  float* GB = (float*)alloc(256 * 4);
  float* WCR = (float*)alloc(128 * 8 * 4);
  float* CC = (float*)alloc(4 * 4);
  float* DIS = (float*)alloc((size_t)NNODES * 4);
  int* EI0 = (int*)alloc((size_t)NEDGES * 4);
  int* EI1 = (int*)alloc((size_t)NEDGES * 4);
  float* EWF = (float*)alloc((size_t)NEDGES * 4);
  int* EMASK = (int*)alloc((size_t)NEDGES * 4);
  int* CNT = (int*)alloc((size_t)NNODES * 4);
  int* INDPTR = (int*)alloc((size_t)(NNODES + 256) * 4);
  int* CURSOR = (int*)alloc((size_t)NNODES * 4);
  int4* PCK4 = (int4*)alloc((size_t)NEDGES * 16);
  int* TOFF = (int*)alloc((size_t)(NNODES / 4) * 4);
  int* BSUM = (int*)alloc((size_t)64 * 4);
  int* BOFF = (int*)alloc((size_t)64 * 4);
  float* SCORE = (float*)alloc((size_t)NNODES * 4);
  int* NEWID = (int*)alloc((size_t)NNODES * 4);
  int* SELI = (int*)alloc((size_t)16384 * 4);
  float* GATEV = (float*)alloc((size_t)16384 * 4);
  float* REPS0 = (float*)alloc((size_t)NB * 256 * 4);
  float* REPS1 = (float*)alloc((size_t)NB * 256 * 4);
  float* RPART = (float*)alloc((size_t)NB * RSPLIT * 256 * 4);
  float* PART1 = (float*)alloc((size_t)256 * 128 * 4);
  float* PART2 = (float*)alloc((size_t)256 * 128 * 4);
  float* MU = (float*)alloc(128 * 4);
  float* RSTD = (float*)alloc(128 * 4);
  float* WN = (float*)alloc(256);
  const int ws_ok = (ws_size >= off) ? 1 : 0;

  edge_init<<<NEDGES / 256, 256, 0, stream>>>(edge_index, edge_weight, EI0, EI1, EWF, EMASK);
  if (hipGetLastError() != hipSuccess) {
    stream = (hipStream_t)0;
    edge_init<<<NEDGES / 256, 256, 0, stream>>>(edge_index, edge_weight, EI0, EI1, EWF, EMASK);
    (void)hipGetLastError();
  }

  if (!ws_ok) {
    fill_f32<<<(out_size + 255) / 256, 256, 0, stream>>>(out, 3000.f, out_size);
    return;
  }

  // Build CSR + degree norm for the current edge set (only changes at pools).
  auto build_graph = [&](int n) {
    fill_dc<<<(n + 255) / 256, 256, 0, stream>>>(DIS, CNT, n);
    deg_cnt<<<NEDGES / 256, 256, 0, stream>>>(EI0, EI1, EMASK, DIS, CNT);
    scan_p1<<<n / 1024, 256, 0, stream>>>(CNT, DIS, TOFF, BSUM);
    scan_p2<<<1, 64, 0, stream>>>(BSUM, BOFF, n / 1024, INDPTR, n);
    scan_p3<<<n / 1024, 256, 0, stream>>>(CNT, TOFF, BOFF, INDPTR, CURSOR);
    csr_fill<<<NEDGES / 256, 256, 0, stream>>>(EI0, EI1, EMASK, EWF, DIS, CURSOR, PCK4);
  };

  auto conv = [&](int n, const float* Ain, int K0, float* Pout, const float* lw,
                  const float* lb, int l) {
    const float* qwl = q_w + (size_t)l * 128 * 512;
    const float* qbl = q_b + (size_t)l * 512;
    const float* kwl = k_w + (size_t)l * 128 * 512;
    const float* kbl = k_b + (size_t)l * 512;
    const float* vwl = v_w + (size_t)l * 128 * 512;
    const float* vbl = v_b + (size_t)l * 512;
    const float* ewl = e_w + (size_t)l * 64 * 512;
    const float* ebl = e_b + (size_t)l * 512;
    const float* swl = s_w + (size_t)l * 128 * 512;
    const float* sbl = s_b + (size_t)l * 512;
    const float* trwl = tr_w + (size_t)l * 512 * 128;
    const float* trbl = tr_b + (size_t)l * 128;

    prep_all<<<388, 256, 0, stream>>>(qwl, kwl, ewl, qbl, kbl, ebl, CtT, BtT, GB, WCR, CC);
    const int wtot = K0 * 128 + 229376;
    wsplit_all<<<(wtot + 255) / 256, 256, 0, stream>>>(lw, K0, vwl, ewl, swl, trwl,
                                                       lwT, WvT, EWmT, SwT, TrT);

    mgemm<<<dim3(n / 128, 1), 256, 0, stream>>>(Ain, lwT, lb, XL, n, K0, 128, 0);
    mgemm<<<dim3(n / 128, 4), 256, 0, stream>>>(XL, CtT, nullptr, U, n, 128, 512, 0);
    mgemm<<<dim3(n / 128, 2), 256, 0, stream>>>(XL, BtT, GB, G, n, 128, 256, 0);
    node_scalars<<<n / 32, 256, 0, stream>>>(XL, WCR, CC, SCV, n);

    fused_attn_light<<<n, 256, 0, stream>>>(PCK4, INDPTR, edge_attr, XL,
                                            U, G, SCV, DIS, XW, DEN);

    for (int cb = 0; cb < n; cb += CH) {
      mattn<<<dim3(CH / 128, 4), 256, 0, stream>>>(U, G, XL, XW, DEN, WvT, EWmT, SwT,
                                                   vbl, ebl, sbl, ATTN, cb);
      mgemm<<<dim3(CH / 128, 1), 256, 0, stream>>>(ATTN, TrT, trbl,
                                                   Pout + (size_t)cb * 128, CH, 512,
                                                   128, 1);
    }
    bn_accum<<<256, 256, 0, stream>>>(Pout, PART1, PART2, n);
    bn_final<<<1, 128, 0, stream>>>(PART1, PART2, MU, RSTD, n);
    bn_apply<<<(n * 128) / 256, 256, 0, stream>>>(Pout, MU, RSTD, bn_g + l * 128,
                                                  bn_b + l * 128, n);
  };

  auto pool = [&](int pi, const float* hSrc, float* hDst, int nOld, int M, float* reps) {
    wnorm_kernel<<<1, 128, 0, stream>>>(pool_w + pi * 128, WN);
    score_kernel<<<(nOld + 255) / 256, 256, 0, stream>>>(hSrc, pool_w + pi * 128, WN,
                                                         SCORE, nOld);
    fill_i32<<<(nOld + 255) / 256, 256, 0, stream>>>(NEWID, -1, nOld);
    topk_kernel<<<NB, 512, 0, stream>>>(SCORE, GATEV, SELI, NEWID, M);
    int nNew = nOld / 2;
    gate_kernel<<<(nNew * 128) / 256, 256, 0, stream>>>(hSrc, GATEV, SELI, hDst, nNew);
    relabel_kernel<<<NEDGES / 256, 256, 0, stream>>>(EI0, EI1, EWF, EMASK, NEWID);
    reps_partial<<<NB * RSPLIT, 128, 0, stream>>>(hDst, RPART, M / 2);
    reps_final<<<NB, 128, 0, stream>>>(RPART, reps, M / 2);
  };

  build_graph(NNODES);
  conv(NNODES, x, 256, P0, lin0_w, lin0_b, 0);
  conv(NNODES, P0, 128, P1, lin_w, lin_b, 1);
  pool(0, P1, P0, NNODES, 1024, REPS0);
  build_graph(16384);
  conv(16384, P0, 128, P1, lin_w + 128 * 128, lin_b + 128, 2);
  conv(16384, P1, 128, P0, lin_w + 2 * 128 * 128, lin_b + 2 * 128, 3);
  pool(1, P0, P1, 16384, 512, REPS1);

  final_out<<<NB * 256 / 256, 256, 0, stream>>>(REPS0, REPS1, out);

  if (hipGetLastError() != hipSuccess) {
    hipMemsetAsync(d_out, 0x45, (size_t)out_size * 4, stream);
  }
}

// Round 8
// 1297.093 us; speedup vs baseline: 1.2454x; 1.2439x over previous
//
#include <hip/hip_runtime.h>
#include <math.h>
#include <cstddef>

#define NNODES 32768
#define NEDGES 262144
#define NB 32
#define CH 8192  // epilogue chunk rows (fallback when workspace is tight)
#define RSPLIT 16

typedef _Float16 f16x4 __attribute__((ext_vector_type(4)));
typedef _Float16 f16x8 __attribute__((ext_vector_type(8)));
typedef float f32x4 __attribute__((ext_vector_type(4)));

__device__ __forceinline__ void load8f(const float* p, float* o) {
  float4 a = *reinterpret_cast<const float4*>(p);
  float4 b = *reinterpret_cast<const float4*>(p + 4);
  o[0] = a.x; o[1] = a.y; o[2] = a.z; o[3] = a.w;
  o[4] = b.x; o[5] = b.y; o[6] = b.z; o[7] = b.w;
}

__global__ void GraphEncoder_82575041233261_kernel() {}

__global__ void fill_f32(float* p, float v, int n) {
  int i = blockIdx.x * blockDim.x + threadIdx.x;
  if (i < n) p[i] = v;
}
__global__ void fill_i32(int* p, int v, int n) {
  int i = blockIdx.x * blockDim.x + threadIdx.x;
  if (i < n) p[i] = v;
}
__global__ void fill_dc(float* dis, int* cnt, int n) {
  int i = blockIdx.x * blockDim.x + threadIdx.x;
  if (i < n) { dis[i] = 0.f; cnt[i] = 0; }
}

__global__ void edge_init(const int* __restrict__ ei, const float* __restrict__ ew,
                          int* ei0, int* ei1, float* ewf, int* emask) {
  int e = blockIdx.x * blockDim.x + threadIdx.x;
  if (e >= NEDGES) return;
  ei0[e] = ei[e];
  ei1[e] = ei[NEDGES + e];
  ewf[e] = ew[e];
  emask[e] = 1;
}

// ================= split-f16 MFMA GEMM machinery =================
struct MTile {
  _Float16 Ah[128][40];
  _Float16 Al[128][40];
  _Float16 Bh[128][40];
  _Float16 Bl[128][40];
};

__device__ __forceinline__ void stageA(MTile& sm, const float* __restrict__ A,
                                       int lda, int tid) {
#pragma unroll
  for (int i = 0; i < 4; i++) {
    int flat = tid + i * 256;            // 1024 float4 = 128 rows x 32 k
    int r = flat >> 3, c4 = (flat & 7) << 2;
    float4 v = *reinterpret_cast<const float4*>(A + (size_t)r * lda + c4);
    _Float16 h0 = (_Float16)v.x, h1 = (_Float16)v.y;
    _Float16 h2 = (_Float16)v.z, h3 = (_Float16)v.w;
    f16x4 hv = {h0, h1, h2, h3};
    f16x4 lv = {(_Float16)(v.x - (float)h0), (_Float16)(v.y - (float)h1),
                (_Float16)(v.z - (float)h2), (_Float16)(v.w - (float)h3)};
    *reinterpret_cast<f16x4*>(&sm.Ah[r][c4]) = hv;
    *reinterpret_cast<f16x4*>(&sm.Al[r][c4]) = lv;
  }
}

__device__ __forceinline__ void stageB(MTile& sm, const _Float16* __restrict__ th,
                                       const _Float16* __restrict__ tl, int Kw,
                                       int tid) {
#pragma unroll
  for (int i = 0; i < 4; i++) {
    int flat = tid + i * 256;            // 1024 chunks of 8 halfs (hi then lo)
    int sel = flat >> 9;                 // uniform per i
    int cc = (flat >> 2) & 127, kc = (flat & 3) << 3;
    const _Float16* s = (sel ? tl : th) + (size_t)cc * Kw + kc;
    f16x8 v = *reinterpret_cast<const f16x8*>(s);
    if (sel)
      *reinterpret_cast<f16x8*>(&sm.Bl[cc][kc]) = v;
    else
      *reinterpret_cast<f16x8*>(&sm.Bh[cc][kc]) = v;
  }
}

__device__ __forceinline__ void mcompute(MTile& sm, f32x4 acc[4][4], int wm,
                                         int wn, int fr, int fq) {
  f16x8 ah[4], al[4], bh[4], bl[4];
#pragma unroll
  for (int m = 0; m < 4; m++) {
    ah[m] = *reinterpret_cast<const f16x8*>(&sm.Ah[wm + m * 16 + fr][fq * 8]);
    al[m] = *reinterpret_cast<const f16x8*>(&sm.Al[wm + m * 16 + fr][fq * 8]);
  }
#pragma unroll
  for (int nn = 0; nn < 4; nn++) {
    bh[nn] = *reinterpret_cast<const f16x8*>(&sm.Bh[wn + nn * 16 + fr][fq * 8]);
    bl[nn] = *reinterpret_cast<const f16x8*>(&sm.Bl[wn + nn * 16 + fr][fq * 8]);
  }
#pragma unroll
  for (int m = 0; m < 4; m++)
#pragma unroll
    for (int nn = 0; nn < 4; nn++) {
      acc[m][nn] = __builtin_amdgcn_mfma_f32_16x16x32_f16(ah[m], bh[nn], acc[m][nn], 0, 0, 0);
      acc[m][nn] = __builtin_amdgcn_mfma_f32_16x16x32_f16(ah[m], bl[nn], acc[m][nn], 0, 0, 0);
      acc[m][nn] = __builtin_amdgcn_mfma_f32_16x16x32_f16(al[m], bh[nn], acc[m][nn], 0, 0, 0);
    }
}

// C[n,M] = A[n,K] @ W + bias (relu optional). W pre-split transposed WT[2][M][K].
__global__ __launch_bounds__(256) void mgemm(
    const float* __restrict__ A, const _Float16* __restrict__ WT,
    const float* __restrict__ bias, float* __restrict__ C,
    int n, int K, int M, int relu) {
  __shared__ MTile sm;
  const int tid = threadIdx.x;
  const int lane = tid & 63, w = tid >> 6;
  const int wm = (w >> 1) << 6, wn = (w & 1) << 6;
  const int fr = lane & 15, fq = lane >> 4;
  const int row0 = blockIdx.x * 128, col0 = blockIdx.y * 128;
  const _Float16* th = WT + (size_t)col0 * K;
  const _Float16* tl = WT + (size_t)M * K + (size_t)col0 * K;
  const float* Ab = A + (size_t)row0 * K;
  f32x4 acc[4][4];
#pragma unroll
  for (int m = 0; m < 4; m++)
#pragma unroll
    for (int nn = 0; nn < 4; nn++) acc[m][nn] = (f32x4){0.f, 0.f, 0.f, 0.f};
  for (int kt = 0; kt < K; kt += 32) {
    stageA(sm, Ab + kt, K, tid);
    stageB(sm, th + kt, tl + kt, K, tid);
    __syncthreads();
    mcompute(sm, acc, wm, wn, fr, fq);
    __syncthreads();
  }
#pragma unroll
  for (int nn = 0; nn < 4; nn++) {
    const int col = col0 + wn + nn * 16 + fr;
    const float b = bias ? bias[col] : 0.f;
#pragma unroll
    for (int m = 0; m < 4; m++)
#pragma unroll
      for (int j = 0; j < 4; j++) {
        int row = row0 + wm + m * 16 + fq * 4 + j;
        float v = acc[m][nn][j] + b;
        if (relu) v = fmaxf(v, 0.f);
        C[(size_t)row * M + col] = v;
      }
  }
}

// attn epilogue GEMM, MFMA version. BN=128 = one head per col-block.
__global__ __launch_bounds__(256) void mattn(
    const float* __restrict__ Z, const float* __restrict__ WS,
    const float* __restrict__ XLv, const float* __restrict__ XW,
    const float* __restrict__ DEN, const _Float16* __restrict__ WvT,
    const _Float16* __restrict__ EWmT, const _Float16* __restrict__ SwT,
    const float* __restrict__ vb, const float* __restrict__ eb,
    const float* __restrict__ sb, float* __restrict__ ATTN, int rowBase) {
  __shared__ MTile sm;
  const int tid = threadIdx.x;
  const int lane = tid & 63, w = tid >> 6;
  const int wm = (w >> 1) << 6, wn = (w & 1) << 6;
  const int fr = lane & 15, fq = lane >> 4;
  const int h = blockIdx.y;
  const int col0 = h << 7;
  const int rloc0 = blockIdx.x * 128;
  const int row0 = rowBase + rloc0;
  f32x4 acc[4][4];
#pragma unroll
  for (int m = 0; m < 4; m++)
#pragma unroll
    for (int nn = 0; nn < 4; nn++) acc[m][nn] = (f32x4){0.f, 0.f, 0.f, 0.f};
  // phase A: K=128 over Z (head slice)
  {
    const float* Ab = Z + (size_t)row0 * 512 + col0;
    const _Float16* th = WvT + (size_t)col0 * 128;
    const _Float16* tl = WvT + (size_t)512 * 128 + (size_t)col0 * 128;
    for (int kt = 0; kt < 128; kt += 32) {
      stageA(sm, Ab + kt, 512, tid);
      stageB(sm, th + kt, tl + kt, 128, tid);
      __syncthreads();
      mcompute(sm, acc, wm, wn, fr, fq);
      __syncthreads();
    }
  }
  // phase B: K=64 over WS (head slice)
  {
    const float* Ab = WS + (size_t)row0 * 256 + (h << 6);
    const _Float16* th = EWmT + (size_t)col0 * 64;
    const _Float16* tl = EWmT + (size_t)512 * 64 + (size_t)col0 * 64;
    for (int kt = 0; kt < 64; kt += 32) {
      stageA(sm, Ab + kt, 256, tid);
      stageB(sm, th + kt, tl + kt, 64, tid);
      __syncthreads();
      mcompute(sm, acc, wm, wn, fr, fq);
      __syncthreads();
    }
  }
  // mid: den scaling + biases
  {
    float vbe[4], sbv[4];
#pragma unroll
    for (int nn = 0; nn < 4; nn++) {
      int col = col0 + wn + nn * 16 + fr;
      vbe[nn] = vb[col] + eb[col];
      sbv[nn] = sb[col];
    }
#pragma unroll
    for (int m = 0; m < 4; m++)
#pragma unroll
      for (int j = 0; j < 4; j++) {
        int row = row0 + wm + m * 16 + fq * 4 + j;
        float d = DEN[(size_t)row * 4 + h];
        float inv = 1.f / (d + 1e-16f);
#pragma unroll
        for (int nn = 0; nn < 4; nn++)
          acc[m][nn][j] = (acc[m][nn][j] + d * vbe[nn]) * inv + sbv[nn];
      }
  }
  // phase C: K=128 over XL (skip branch), accumulates post-scaling
  {
    const float* Ab = XLv + (size_t)row0 * 128;
    const _Float16* th = SwT + (size_t)col0 * 128;
    const _Float16* tl = SwT + (size_t)512 * 128 + (size_t)col0 * 128;
    for (int kt = 0; kt < 128; kt += 32) {
      stageA(sm, Ab + kt, 128, tid);
      stageB(sm, th + kt, tl + kt, 128, tid);
      __syncthreads();
      mcompute(sm, acc, wm, wn, fr, fq);
      __syncthreads();
    }
  }
#pragma unroll
  for (int nn = 0; nn < 4; nn++) {
    int col = col0 + wn + nn * 16 + fr;
#pragma unroll
    for (int m = 0; m < 4; m++)
#pragma unroll
      for (int j = 0; j < 4; j++) {
        int rl = rloc0 + wm + m * 16 + fq * 4 + j;
        float v = acc[m][nn][j] + XW[(size_t)(rowBase + rl) * 128 + (col & 127)];
        ATTN[(size_t)rl * 512 + col] = v;
      }
  }
}

// ---- merged weight prep: split fp32 W[K][M] -> WT[2][M][K] f16 for all 5 ----
__global__ void wsplit_all(const float* __restrict__ lw, int K0,
                           const float* __restrict__ vw, const float* __restrict__ ew,
                           const float* __restrict__ sw, const float* __restrict__ trw,
                           _Float16* __restrict__ lwT, _Float16* __restrict__ WvT,
                           _Float16* __restrict__ EWmT, _Float16* __restrict__ SwT,
                           _Float16* __restrict__ TrT) {
  int idx = blockIdx.x * 256 + threadIdx.x;
  const float* W; _Float16* T; int K, msh, loc;
  const int s0 = K0 << 7;
  if (idx < s0) { W = lw; T = lwT; K = K0; msh = 7; loc = idx; }
  else if (idx < s0 + 65536) { W = vw; T = WvT; K = 128; msh = 9; loc = idx - s0; }
  else if (idx < s0 + 98304) { W = ew; T = EWmT; K = 64; msh = 9; loc = idx - s0 - 65536; }
  else if (idx < s0 + 163840) { W = sw; T = SwT; K = 128; msh = 9; loc = idx - s0 - 98304; }
  else if (idx < s0 + 229376) { W = trw; T = TrT; K = 512; msh = 7; loc = idx - s0 - 163840; }
  else return;
  int M = 1 << msh;
  int k = loc >> msh, m2 = loc & (M - 1);
  float v = W[loc];
  _Float16 hh = (_Float16)v;
  T[(size_t)m2 * K + k] = hh;
  T[(size_t)M * K + (size_t)m2 * K + k] = (_Float16)(v - (float)hh);
}

// ---- merged folded-weight prep (float4-vectorized inner loops) ----
__global__ __launch_bounds__(256) void prep_all(
    const float* __restrict__ Wq, const float* __restrict__ Wk,
    const float* __restrict__ EWm, const float* __restrict__ bq,
    const float* __restrict__ bk, const float* __restrict__ eb,
    _Float16* __restrict__ CtT, _Float16* __restrict__ BtT,
    float* __restrict__ gb, float* __restrict__ WCR, float* __restrict__ CC) {
  int idx = blockIdx.x * 256 + threadIdx.x;
  if (idx < 65536) {
    int cin = idx >> 9, r = idx & 511, h = r >> 7, co = r & 127;
    const float4* a4 = reinterpret_cast<const float4*>(Wq + cin * 512 + h * 128);
    const float4* b4 = reinterpret_cast<const float4*>(Wk + co * 512 + h * 128);
    float acc = 0.f;
#pragma unroll 8
    for (int c = 0; c < 32; c++) {
      float4 a = a4[c], b = b4[c];
      acc += a.x * b.x + a.y * b.y + a.z * b.z + a.w * b.w;
    }
    _Float16 hh = (_Float16)acc;
    CtT[(size_t)r * 128 + cin] = hh;
    CtT[(size_t)512 * 128 + (size_t)r * 128 + cin] = (_Float16)(acc - (float)hh);
  } else if (idx < 98304) {
    int t = idx - 65536;
    int cin = t >> 8, r = t & 255, h = r >> 6, f = r & 63;
    const float4* a4 = reinterpret_cast<const float4*>(Wq + cin * 512 + h * 128);
    const float4* b4 = reinterpret_cast<const float4*>(EWm + f * 512 + h * 128);
    float acc = 0.f;
#pragma unroll 8
    for (int c = 0; c < 32; c++) {
      float4 a = a4[c], b = b4[c];
      acc += a.x * b.x + a.y * b.y + a.z * b.z + a.w * b.w;
    }
    _Float16 hh = (_Float16)acc;
    BtT[(size_t)r * 128 + cin] = hh;
    BtT[(size_t)256 * 128 + (size_t)r * 128 + cin] = (_Float16)(acc - (float)hh);
    if (cin == 0) {
      const float4* c4 = reinterpret_cast<const float4*>(bq + h * 128);
      float s = 0.f;
#pragma unroll 8
      for (int c = 0; c < 32; c++) {
        float4 a = b4[c], b = c4[c];
        s += a.x * b.x + a.y * b.y + a.z * b.z + a.w * b.w;
      }
      gb[r] = s;
    }
  } else if (idx < 99328) {
    int tid = idx - 98304;
    int cin = tid >> 3, j = tid & 7, h2 = j & 3, isR = j >> 2;
    float acc = 0.f;
    if (isR) {
      for (int c = 0; c < 128; c++)
        acc += Wk[cin * 512 + h2 * 128 + c] * bq[h2 * 128 + c];
    } else {
      for (int c = 0; c < 128; c++)
        acc += Wq[cin * 512 + h2 * 128 + c] * (bk[h2 * 128 + c] + eb[h2 * 128 + c]);
    }
    WCR[cin * 8 + j] = acc;
    if (tid < 4) {
      float s = 0.f;
      for (int c = 0; c < 128; c++)
        s += bq[tid * 128 + c] * (bk[tid * 128 + c] + eb[tid * 128 + c]);
      CC[tid] = s;
    }
  }
}

// SCV[node, j] = XL[node]·WCR[:,j] (+CC for j<4); float4 loads
__global__ __launch_bounds__(256) void node_scalars(const float* __restrict__ XL,
                                                    const float* __restrict__ WCR,
                                                    const float* __restrict__ CC,
                                                    float* __restrict__ SCV, int n) {
  int t = blockIdx.x * 256 + threadIdx.x;
  if (t >= n * 8) return;
  int node = t >> 3, j = t & 7;
  const float4* x4 = reinterpret_cast<const float4*>(XL + (size_t)node * 128);
  float acc = (j < 4) ? CC[j] : 0.f;
#pragma unroll 8
  for (int c = 0; c < 32; c++) {
    float4 v = x4[c];
    acc += v.x * WCR[(c * 4) * 8 + j] + v.y * WCR[(c * 4 + 1) * 8 + j] +
           v.z * WCR[(c * 4 + 2) * 8 + j] + v.w * WCR[(c * 4 + 3) * 8 + j];
  }
  SCV[t] = acc;
}

// merged degree + indegree count
__global__ void deg_cnt(const int* __restrict__ ei0, const int* __restrict__ ei1,
                        const int* __restrict__ emask, float* deg, int* cnt) {
  int e = blockIdx.x * blockDim.x + threadIdx.x;
  if (e >= NEDGES) return;
  if (emask[e]) {
    atomicAdd(&deg[ei0[e]], 1.0f);
    atomicAdd(&cnt[ei1[e]], 1);
  }
}

// ---- parallel 3-phase exclusive scan over cnt (n multiple of 1024) ----
__global__ __launch_bounds__(256) void scan_p1(const int* __restrict__ cnt,
                                               float* __restrict__ dis,
                                               int* __restrict__ toff,
                                               int* __restrict__ bsum) {
  const int b = blockIdx.x, tid = threadIdx.x;
  const int gi = b * 1024 + tid * 4;
  int4 c = *reinterpret_cast<const int4*>(cnt + gi);
  float4 d = *reinterpret_cast<const float4*>(dis + gi);
  float4 dr;
  dr.x = d.x > 0.f ? rsqrtf(d.x) : 0.f;
  dr.y = d.y > 0.f ? rsqrtf(d.y) : 0.f;
  dr.z = d.z > 0.f ? rsqrtf(d.z) : 0.f;
  dr.w = d.w > 0.f ? rsqrtf(d.w) : 0.f;
  *reinterpret_cast<float4*>(dis + gi) = dr;
  int s = c.x + c.y + c.z + c.w;
  __shared__ int sh[256];
  sh[tid] = s;
  __syncthreads();
  for (int dstep = 1; dstep < 256; dstep <<= 1) {
    int t = (tid >= dstep) ? sh[tid - dstep] : 0;
    __syncthreads();
    sh[tid] += t;
    __syncthreads();
  }
  toff[b * 256 + tid] = sh[tid] - s;  // exclusive within block
  if (tid == 255) bsum[b] = sh[255];
}
__global__ void scan_p2(const int* __restrict__ bsum, int* __restrict__ boff,
                        int nb, int* __restrict__ indptr, int n) {
  if (threadIdx.x == 0) {
    int run = 0;
    for (int i = 0; i < nb; i++) { boff[i] = run; run += bsum[i]; }
    indptr[n] = run;
  }
}
__global__ __launch_bounds__(256) void scan_p3(const int* __restrict__ cnt,
                                               const int* __restrict__ toff,
                                               const int* __restrict__ boff,
                                               int* __restrict__ indptr,
                                               int* __restrict__ cursor) {
  const int b = blockIdx.x, tid = threadIdx.x;
  const int gi = b * 1024 + tid * 4;
  int4 c = *reinterpret_cast<const int4*>(cnt + gi);
  int run = boff[b] + toff[b * 256 + tid];
  int4 o;
  o.x = run;
  o.y = run + c.x;
  o.z = o.y + c.y;
  o.w = o.z + c.z;
  *reinterpret_cast<int4*>(indptr + gi) = o;
  *reinterpret_cast<int4*>(cursor + gi) = o;
}

// CSR fill, packed 16B records: PCK[p]={src, e, bits(dis[src]*ewf[e]), 0}
__global__ void csr_fill(const int* __restrict__ ei0, const int* __restrict__ ei1,
                         const int* __restrict__ emask, const float* __restrict__ ewf,
                         const float* __restrict__ dis, int* cursor,
                         int4* __restrict__ pck) {
  int e = blockIdx.x * blockDim.x + threadIdx.x;
  if (e >= NEDGES) return;
  if (!emask[e]) return;
  int p = atomicAdd(&cursor[ei1[e]], 1);
  int r = ei0[e];
  int4 rec;
  rec.x = r;
  rec.y = e;
  rec.z = __float_as_int(dis[r] * ewf[e]);
  rec.w = 0;
  pck[p] = rec;
}

// ---- light attention pass (round-4 best form): one wave per destination node.
// Defer-max online softmax (rescale only when alpha > m+8), 2-edge unroll for
// memory ILP, chunk=16 with per-lane rowS prefetch. ~60 VGPR keeps occupancy.
__global__ __launch_bounds__(256) void fused_attn_light(
    const int4* __restrict__ PCK, const int* __restrict__ indptr,
    const float* __restrict__ EA, const float* __restrict__ XLv,
    float* U, float* G, const float* __restrict__ SCVv,
    const float* __restrict__ DISv, float* __restrict__ XW,
    float* __restrict__ DEN) {
  const int w = threadIdx.x >> 6, lane = threadIdx.x & 63;
  const int h = lane >> 4, t16 = lane & 15;
  const int col = blockIdx.x * 4 + w;
  float u8[8];
  load8f(U + (size_t)col * 512 + lane * 8, u8);
  float4 g4 = *reinterpret_cast<const float4*>(G + (size_t)col * 256 + lane * 4);
  const float colS = SCVv[col * 8 + h];
  const float dcol = DISv[col];
  const int beg = indptr[col], end = indptr[col + 1];
  const float rs = 0.08838834764831845f;  // 1/sqrt(128)
  float m = -3.0e38f, den = 0.f;
  float z8[8] = {0.f, 0.f, 0.f, 0.f, 0.f, 0.f, 0.f, 0.f};
  float w4[4] = {0.f, 0.f, 0.f, 0.f};
  float xw8[8] = {0.f, 0.f, 0.f, 0.f, 0.f, 0.f, 0.f, 0.f};
  for (int base = beg; base < end; base += 16) {
    const int cnt = min(16, end - base);
    const int li = base + min(t16, cnt - 1);
    const int4 rec = PCK[li];
    const float dnl = __int_as_float(rec.z);
    // lane (h,t16) holds rowS of edge t16 for head h -> 1 shfl/edge later
    const float rsv = SCVv[(size_t)rec.x * 8 + 4 + h];
    int i = 0;
    for (; i + 2 <= cnt; i += 2) {
      const int r1 = __shfl(rec.x, i), e1 = __shfl(rec.y, i);
      const int r2 = __shfl(rec.x, i + 1), e2 = __shfl(rec.y, i + 1);
      const float dn1 = __shfl(dnl, i), dn2 = __shfl(dnl, i + 1);
      const float rowS1 = __shfl(rsv, (h << 4) + i);
      const float rowS2 = __shfl(rsv, (h << 4) + i + 1);
      float xr1[8], xr2[8];
      load8f(XLv + (size_t)r1 * 128 + t16 * 8, xr1);
      load8f(XLv + (size_t)r2 * 128 + t16 * 8, xr2);
      float4 ea1 = *reinterpret_cast<const float4*>(EA + (size_t)e1 * 64 + t16 * 4);
      float4 ea2 = *reinterpret_cast<const float4*>(EA + (size_t)e2 * 64 + t16 * 4);
      float p1 = 0.f, p2 = 0.f;
#pragma unroll
      for (int j = 0; j < 8; j++) { p1 += u8[j] * xr1[j]; p2 += u8[j] * xr2[j]; }
      p1 += g4.x * ea1.x + g4.y * ea1.y + g4.z * ea1.z + g4.w * ea1.w;
      p2 += g4.x * ea2.x + g4.y * ea2.y + g4.z * ea2.z + g4.w * ea2.w;
      p1 += __shfl_xor(p1, 1); p2 += __shfl_xor(p2, 1);
      p1 += __shfl_xor(p1, 2); p2 += __shfl_xor(p2, 2);
      p1 += __shfl_xor(p1, 4); p2 += __shfl_xor(p2, 4);
      p1 += __shfl_xor(p1, 8); p2 += __shfl_xor(p2, 8);
      const float a1v = (p1 + colS + rowS1) * rs;
      const float a2v = (p2 + colS + rowS2) * rs;
      const float mx = fmaxf(a1v, a2v);
      if (mx > m + 8.f) {  // rare rescale (uniform within 16-lane head group)
        const float sc = __expf(m - mx);
        den *= sc;
#pragma unroll
        for (int j = 0; j < 8; j++) z8[j] *= sc;
        w4[0] *= sc; w4[1] *= sc; w4[2] *= sc; w4[3] *= sc;
        m = mx;
      }
      const float a1 = __expf(a1v - m);
      const float a2 = __expf(a2v - m);
      den += a1 + a2;
#pragma unroll
      for (int j = 0; j < 8; j++) z8[j] += a1 * xr1[j] + a2 * xr2[j];
      w4[0] += a1 * ea1.x + a2 * ea2.x;
      w4[1] += a1 * ea1.y + a2 * ea2.y;
      w4[2] += a1 * ea1.z + a2 * ea2.z;
      w4[3] += a1 * ea1.w + a2 * ea2.w;
#pragma unroll
      for (int j = 0; j < 8; j++) xw8[j] += dn1 * xr1[j] + dn2 * xr2[j];
    }
    if (i < cnt) {  // remainder edge
      const int r1 = __shfl(rec.x, i), e1 = __shfl(rec.y, i);
      const float dn1 = __shfl(dnl, i);
      const float rowS1 = __shfl(rsv, (h << 4) + i);
      float xr1[8];
      load8f(XLv + (size_t)r1 * 128 + t16 * 8, xr1);
      float4 ea1 = *reinterpret_cast<const float4*>(EA + (size_t)e1 * 64 + t16 * 4);
      float p1 = 0.f;
#pragma unroll
      for (int j = 0; j < 8; j++) p1 += u8[j] * xr1[j];
      p1 += g4.x * ea1.x + g4.y * ea1.y + g4.z * ea1.z + g4.w * ea1.w;
      p1 += __shfl_xor(p1, 1);
      p1 += __shfl_xor(p1, 2);
      p1 += __shfl_xor(p1, 4);
      p1 += __shfl_xor(p1, 8);
      const float a1v = (p1 + colS + rowS1) * rs;
      if (a1v > m + 8.f) {
        const float sc = __expf(m - a1v);
        den *= sc;
#pragma unroll
        for (int j = 0; j < 8; j++) z8[j] *= sc;
        w4[0] *= sc; w4[1] *= sc; w4[2] *= sc; w4[3] *= sc;
        m = a1v;
      }
      const float a1 = __expf(a1v - m);
      den += a1;
#pragma unroll
      for (int j = 0; j < 8; j++) z8[j] += a1 * xr1[j];
      w4[0] += a1 * ea1.x;
      w4[1] += a1 * ea1.y;
      w4[2] += a1 * ea1.z;
      w4[3] += a1 * ea1.w;
#pragma unroll
      for (int j = 0; j < 8; j++) xw8[j] += dn1 * xr1[j];
    }
  }
  float4 o1, o2;
  o1.x = z8[0]; o1.y = z8[1]; o1.z = z8[2]; o1.w = z8[3];
  o2.x = z8[4]; o2.y = z8[5]; o2.z = z8[6]; o2.w = z8[7];
  *reinterpret_cast<float4*>(U + (size_t)col * 512 + lane * 8) = o1;
  *reinterpret_cast<float4*>(U + (size_t)col * 512 + lane * 8 + 4) = o2;
  float4 ow;
  ow.x = w4[0]; ow.y = w4[1]; ow.z = w4[2]; ow.w = w4[3];
  *reinterpret_cast<float4*>(G + (size_t)col * 256 + lane * 4) = ow;
  if (h == 0) {  // degree-norm branch: channels t16*8..t16*8+8
    float4 x1, x2;
    x1.x = xw8[0] * dcol; x1.y = xw8[1] * dcol; x1.z = xw8[2] * dcol; x1.w = xw8[3] * dcol;
    x2.x = xw8[4] * dcol; x2.y = xw8[5] * dcol; x2.z = xw8[6] * dcol; x2.w = xw8[7] * dcol;
    *reinterpret_cast<float4*>(XW + (size_t)col * 128 + t16 * 8) = x1;
    *reinterpret_cast<float4*>(XW + (size_t)col * 128 + t16 * 8 + 4) = x2;
  }
  if (t16 == 0) DEN[col * 4 + h] = den;
}

// ---- batchnorm (in-place) ----
__global__ __launch_bounds__(256) void bn_accum(const float* __restrict__ x,
                                                float* __restrict__ part1,
                                                float* __restrict__ part2, int n) {
  __shared__ float sh1[256], sh2[256];
  int c = threadIdx.x & 127;
  int half = threadIdx.x >> 7;
  float a = 0.f, b = 0.f;
  for (int i = blockIdx.x * 2 + half; i < n; i += gridDim.x * 2) {
    float v = x[(size_t)i * 128 + c];
    a += v;
    b += v * v;
  }
  sh1[threadIdx.x] = a;
  sh2[threadIdx.x] = b;
  __syncthreads();
  if (half == 0) {
    part1[blockIdx.x * 128 + c] = a + sh1[threadIdx.x + 128];
    part2[blockIdx.x * 128 + c] = b + sh2[threadIdx.x + 128];
  }
}
__global__ void bn_final(const float* __restrict__ part1, const float* __restrict__ part2,
                         float* mu, float* rstd, int n) {
  int c = threadIdx.x;
  if (c >= 128) return;
  float s1 = 0.f, s2 = 0.f;
#pragma unroll 8
  for (int b = 0; b < 256; b++) {
    s1 += part1[b * 128 + c];
    s2 += part2[b * 128 + c];
  }
  float m = s1 / (float)n;
  mu[c] = m;
  float var = s2 / (float)n - m * m;
  rstd[c] = rsqrtf(var + 1e-5f);
}
__global__ void bn_apply(float* x, const float* __restrict__ mu,
                         const float* __restrict__ rstd, const float* __restrict__ g,
                         const float* __restrict__ b, int n) {
  int t = blockIdx.x * blockDim.x + threadIdx.x;
  if (t >= n * 128) return;
  int c = t & 127;
  x[t] = g[c] * (x[t] - mu[c]) * rstd[c] + b[c];
}

// ---- pooling ----
__global__ void wnorm_kernel(const float* __restrict__ w, float* wn) {
  __shared__ float s[128];
  int t = threadIdx.x;
  float v = w[t];
  s[t] = v * v;
  __syncthreads();
  for (int st = 64; st > 0; st >>= 1) {
    if (t < st) s[t] += s[t + st];
    __syncthreads();
  }
  if (t == 0) wn[0] = sqrtf(s[0]) + 1e-16f;
}
__global__ void score_kernel(const float* __restrict__ h, const float* __restrict__ w,
                             const float* __restrict__ wn, float* s, int n) {
  int i = blockIdx.x * blockDim.x + threadIdx.x;
  if (i >= n) return;
  const float4* hr = reinterpret_cast<const float4*>(h + (size_t)i * 128);
  const float4* wr = reinterpret_cast<const float4*>(w);
  float d = 0.f;
  for (int c = 0; c < 32; c++) {
    float4 a = hr[c], b = wr[c];
    d += a.x * b.x + a.y * b.y + a.z * b.z + a.w * b.w;
  }
  s[i] = tanhf(d / wn[0]);
}
__global__ __launch_bounds__(512) void topk_kernel(const float* __restrict__ s,
                                                   float* gateVal, int* selIdx,
                                                   int* newid, int M) {
  __shared__ float sv[1024];
  __shared__ int si[1024];
  const int g = blockIdx.x;
  const int k = M >> 1;
  for (int t = threadIdx.x; t < 1024; t += 512) {
    if (t < M) {
      sv[t] = s[(size_t)g * M + t];
      si[t] = t;
    } else {
      sv[t] = -3.4e38f;
      si[t] = 0x7fffffff;
    }
  }
  __syncthreads();
  for (int kk = 2; kk <= 1024; kk <<= 1) {
    for (int j = kk >> 1; j > 0; j >>= 1) {
      for (int t = threadIdx.x; t < 1024; t += 512) {
        int p = t ^ j;
        if (p > t) {
          float va = sv[t], vb2 = sv[p];
          int ia = si[t], ib = si[p];
          bool beforeBA = (vb2 > va) || (vb2 == va && ib < ia);
          bool beforeAB = (va > vb2) || (va == vb2 && ia < ib);
          bool dir = ((t & kk) == 0);
          bool sw = dir ? beforeBA : beforeAB;
          if (sw) {
            sv[t] = vb2;
            sv[p] = va;
            si[t] = ib;
            si[p] = ia;
          }
        }
      }
      __syncthreads();
    }
  }
  for (int j = threadIdx.x; j < k; j += 512) {
    int oldg = g * M + si[j];
    int newg = g * k + j;
    gateVal[newg] = sv[j];
    selIdx[newg] = oldg;
    newid[oldg] = newg;
  }
}
__global__ void gate_kernel(const float* __restrict__ hOld, const float* __restrict__ gv,
                            const int* __restrict__ sel, float* __restrict__ hNew,
                            int nNew) {
  int t = blockIdx.x * blockDim.x + threadIdx.x;
  if (t >= nNew * 128) return;
  int i = t >> 7, c = t & 127;
  hNew[t] = hOld[(size_t)sel[i] * 128 + c] * gv[i];
}
__global__ void relabel_kernel(int* ei0, int* ei1, float* ewf, int* emask,
                               const int* __restrict__ newid) {
  int e = blockIdx.x * blockDim.x + threadIdx.x;
  if (e >= NEDGES) return;
  int nr = newid[ei0[e]];
  int nc = newid[ei1[e]];
  int keep = (nr >= 0 && nc >= 0 && emask[e]) ? 1 : 0;
  ei0[e] = keep ? nr : 0;
  ei1[e] = keep ? nc : 0;
  ewf[e] = keep ? ewf[e] : 0.f;
  emask[e] = keep;
}
// ---- reps: split row-reduction for occupancy ----
__global__ void reps_partial(const float* __restrict__ h, float* __restrict__ rpart,
                             int k) {
  int g = blockIdx.x / RSPLIT, s = blockIdx.x % RSPLIT;
  int c = threadIdx.x;
  int per = k / RSPLIT;
  int j0 = s * per;
  float mx = -3.4e38f, sm = 0.f;
  for (int j = j0; j < j0 + per; j++) {
    float v = h[(size_t)(g * k + j) * 128 + c];
    mx = fmaxf(mx, v);
    sm += v;
  }
  rpart[(size_t)(g * RSPLIT + s) * 256 + c] = mx;
  rpart[(size_t)(g * RSPLIT + s) * 256 + 128 + c] = sm;
}
__global__ void reps_final(const float* __restrict__ rpart, float* __restrict__ rep,
                           int k) {
  int g = blockIdx.x, c = threadIdx.x;
  float mx = -3.4e38f, sm = 0.f;
  for (int s = 0; s < RSPLIT; s++) {
    mx = fmaxf(mx, rpart[(size_t)(g * RSPLIT + s) * 256 + c]);
    sm += rpart[(size_t)(g * RSPLIT + s) * 256 + 128 + c];
  }
  rep[g * 256 + c] = mx;
  rep[g * 256 + 128 + c] = sm / (float)k;
}
__global__ void final_out(const float* __restrict__ r0, const float* __restrict__ r1,
                          float* out) {
  int t = blockIdx.x * blockDim.x + threadIdx.x;
  if (t >= NB * 256) return;
  out[t] = r0[t] + r1[t];
}

extern "C" __attribute__((visibility("default")))
void kernel_launch(void* const* d_in, const int* in_sizes, int n_in,
                   void* d_out, int out_size, void* d_ws, size_t ws_size,
                   hipStream_t stream) {
  (void)hipGetLastError();

  const float* x = (const float*)d_in[0];
  const float* edge_attr = (const float*)d_in[1];
  const int* edge_index = (const int*)d_in[2];
  const float* edge_weight = (const float*)d_in[3];
  const float* lin0_w = (const float*)d_in[5];
  const float* lin0_b = (const float*)d_in[6];
  const float* lin_w = (const float*)d_in[7];
  const float* lin_b = (const float*)d_in[8];
  const float* q_w = (const float*)d_in[9];
  const float* q_b = (const float*)d_in[10];
  const float* k_w = (const float*)d_in[11];
  const float* k_b = (const float*)d_in[12];
  const float* v_w = (const float*)d_in[13];
  const float* v_b = (const float*)d_in[14];
  const float* e_w = (const float*)d_in[15];
  const float* e_b = (const float*)d_in[16];
  const float* s_w = (const float*)d_in[17];
  const float* s_b = (const float*)d_in[18];
  const float* tr_w = (const float*)d_in[19];
  const float* tr_b = (const float*)d_in[20];
  const float* bn_g = (const float*)d_in[21];
  const float* bn_b = (const float*)d_in[22];
  const float* pool_w = (const float*)d_in[23];
  (void)in_sizes; (void)n_in;

  float* out = (float*)d_out;

  size_t off = 0;
  auto alloc = [&](size_t bytes) -> void* {
    void* r = (char*)d_ws + off;
    off += (bytes + 255) & ~(size_t)255;
    return r;
  };
  float* P0 = (float*)alloc((size_t)NNODES * 128 * 4);
  float* P1 = (float*)alloc((size_t)NNODES * 128 * 4);
  float* XL = (float*)alloc((size_t)NNODES * 128 * 4);
  float* U = (float*)alloc((size_t)NNODES * 512 * 4);  // becomes Z after light pass
  float* G = (float*)alloc((size_t)NNODES * 256 * 4);  // becomes WS after light pass
  float* XW = (float*)alloc((size_t)NNODES * 128 * 4);
  float* DEN = (float*)alloc((size_t)NNODES * 4 * 4);
  float* SCV = (float*)alloc((size_t)NNODES * 8 * 4);
  _Float16* CtT = (_Float16*)alloc((size_t)2 * 512 * 128 * 2);
  _Float16* BtT = (_Float16*)alloc((size_t)2 * 256 * 128 * 2);
  _Float16* lwT = (_Float16*)alloc((size_t)2 * 128 * 256 * 2);
  _Float16* WvT = (_Float16*)alloc((size_t)2 * 512 * 128 * 2);
  _Float16* EWmT = (_Float16*)alloc((size_t)2 * 512 * 64 * 2);
  _Float16* SwT = (_Float16*)alloc((size_t)2 * 512 * 128 * 2);
  _Float16* TrT = (_Float16*)alloc((size_t)2 * 128 * 512 * 2);
  float* GB = (float*)alloc(256 * 4);
  float* WCR = (float*)alloc(128 * 8 * 4);
  float* CC = (float*)alloc(4 * 4);
  float* DIS = (float*)alloc((size_t)NNODES * 4);
  int* EI0 = (int*)alloc((size_t)NEDGES * 4);
  int* EI1 = (int*)alloc((size_t)NEDGES * 4);
  float* EWF = (float*)alloc((size_t)NEDGES * 4);
  int* EMASK = (int*)alloc((size_t)NEDGES * 4);
  int* CNT = (int*)alloc((size_t)NNODES * 4);
  int* INDPTR = (int*)alloc((size_t)(NNODES + 256) * 4);
  int* CURSOR = (int*)alloc((size_t)NNODES * 4);
  int4* PCK4 = (int4*)alloc((size_t)NEDGES * 16);
  int* TOFF = (int*)alloc((size_t)(NNODES / 4) * 4);
  int* BSUM = (int*)alloc((size_t)64 * 4);
  int* BOFF = (int*)alloc((size_t)64 * 4);
  float* SCORE = (float*)alloc((size_t)NNODES * 4);
  int* NEWID = (int*)alloc((size_t)NNODES * 4);
  int* SELI = (int*)alloc((size_t)16384 * 4);
  float* GATEV = (float*)alloc((size_t)16384 * 4);
  float* REPS0 = (float*)alloc((size_t)NB * 256 * 4);
  float* REPS1 = (float*)alloc((size_t)NB * 256 * 4);
  float* RPART = (float*)alloc((size_t)NB * RSPLIT * 256 * 4);
  float* PART1 = (float*)alloc((size_t)256 * 128 * 4);
  float* PART2 = (float*)alloc((size_t)256 * 128 * 4);
  float* MU = (float*)alloc(128 * 4);
  float* RSTD = (float*)alloc(128 * 4);
  float* WN = (float*)alloc(256);
  // ATTN last, runtime-sized: full n removes the chunk serialization (1024-block
  // mattn + 256-block tr-GEMM per conv) if the workspace has room, else CH=8192.
  size_t rem = (ws_size > off) ? ws_size - off : 0;
  const int CHe = (rem >= (size_t)NNODES * 512 * 4 + 512) ? NNODES : CH;
  float* ATTN = (float*)alloc((size_t)CHe * 512 * 4);
  const int ws_ok = (ws_size >= off) ? 1 : 0;

  edge_init<<<NEDGES / 256, 256, 0, stream>>>(edge_index, edge_weight, EI0, EI1, EWF, EMASK);
  if (hipGetLastError() != hipSuccess) {
    stream = (hipStream_t)0;
    edge_init<<<NEDGES / 256, 256, 0, stream>>>(edge_index, edge_weight, EI0, EI1, EWF, EMASK);
    (void)hipGetLastError();
  }

  if (!ws_ok) {
    fill_f32<<<(out_size + 255) / 256, 256, 0, stream>>>(out, 3000.f, out_size);
    return;
  }

  // Build CSR + degree norm for the current edge set (only changes at pools).
  auto build_graph = [&](int n) {
    fill_dc<<<(n + 255) / 256, 256, 0, stream>>>(DIS, CNT, n);
    deg_cnt<<<NEDGES / 256, 256, 0, stream>>>(EI0, EI1, EMASK, DIS, CNT);
    scan_p1<<<n / 1024, 256, 0, stream>>>(CNT, DIS, TOFF, BSUM);
    scan_p2<<<1, 64, 0, stream>>>(BSUM, BOFF, n / 1024, INDPTR, n);
    scan_p3<<<n / 1024, 256, 0, stream>>>(CNT, TOFF, BOFF, INDPTR, CURSOR);
    csr_fill<<<NEDGES / 256, 256, 0, stream>>>(EI0, EI1, EMASK, EWF, DIS, CURSOR, PCK4);
  };

  auto conv = [&](int n, const float* Ain, int K0, float* Pout, const float* lw,
                  const float* lb, int l) {
    const float* qwl = q_w + (size_t)l * 128 * 512;
    const float* qbl = q_b + (size_t)l * 512;
    const float* kwl = k_w + (size_t)l * 128 * 512;
    const float* kbl = k_b + (size_t)l * 512;
    const float* vwl = v_w + (size_t)l * 128 * 512;
    const float* vbl = v_b + (size_t)l * 512;
    const float* ewl = e_w + (size_t)l * 64 * 512;
    const float* ebl = e_b + (size_t)l * 512;
    const float* swl = s_w + (size_t)l * 128 * 512;
    const float* sbl = s_b + (size_t)l * 512;
    const float* trwl = tr_w + (size_t)l * 512 * 128;
    const float* trbl = tr_b + (size_t)l * 128;

    prep_all<<<388, 256, 0, stream>>>(qwl, kwl, ewl, qbl, kbl, ebl, CtT, BtT, GB, WCR, CC);
    const int wtot = K0 * 128 + 229376;
    wsplit_all<<<(wtot + 255) / 256, 256, 0, stream>>>(lw, K0, vwl, ewl, swl, trwl,
                                                       lwT, WvT, EWmT, SwT, TrT);

    mgemm<<<dim3(n / 128, 1), 256, 0, stream>>>(Ain, lwT, lb, XL, n, K0, 128, 0);
    mgemm<<<dim3(n / 128, 4), 256, 0, stream>>>(XL, CtT, nullptr, U, n, 128, 512, 0);
    mgemm<<<dim3(n / 128, 2), 256, 0, stream>>>(XL, BtT, GB, G, n, 128, 256, 0);
    node_scalars<<<n / 32, 256, 0, stream>>>(XL, WCR, CC, SCV, n);

    fused_attn_light<<<n / 4, 256, 0, stream>>>(PCK4, INDPTR, edge_attr, XL,
                                                U, G, SCV, DIS, XW, DEN);

    for (int cb = 0; cb < n; cb += CHe) {
      const int rows = (n - cb < CHe) ? (n - cb) : CHe;
      mattn<<<dim3(rows / 128, 4), 256, 0, stream>>>(U, G, XL, XW, DEN, WvT, EWmT, SwT,
                                                     vbl, ebl, sbl, ATTN, cb);
      mgemm<<<dim3(rows / 128, 1), 256, 0, stream>>>(ATTN, TrT, trbl,
                                                     Pout + (size_t)cb * 128, rows, 512,
                                                     128, 1);
    }
    bn_accum<<<256, 256, 0, stream>>>(Pout, PART1, PART2, n);
    bn_final<<<1, 128, 0, stream>>>(PART1, PART2, MU, RSTD, n);
    bn_apply<<<(n * 128) / 256, 256, 0, stream>>>(Pout, MU, RSTD, bn_g + l * 128,
                                                  bn_b + l * 128, n);
  };

  auto pool = [&](int pi, const float* hSrc, float* hDst, int nOld, int M, float* reps) {
    wnorm_kernel<<<1, 128, 0, stream>>>(pool_w + pi * 128, WN);
    score_kernel<<<(nOld + 255) / 256, 256, 0, stream>>>(hSrc, pool_w + pi * 128, WN,
                                                         SCORE, nOld);
    fill_i32<<<(nOld + 255) / 256, 256, 0, stream>>>(NEWID, -1, nOld);
    topk_kernel<<<NB, 512, 0, stream>>>(SCORE, GATEV, SELI, NEWID, M);
    int nNew = nOld / 2;
    gate_kernel<<<(nNew * 128) / 256, 256, 0, stream>>>(hSrc, GATEV, SELI, hDst, nNew);
    relabel_kernel<<<NEDGES / 256, 256, 0, stream>>>(EI0, EI1, EWF, EMASK, NEWID);
    reps_partial<<<NB * RSPLIT, 128, 0, stream>>>(hDst, RPART, M / 2);
    reps_final<<<NB, 128, 0, stream>>>(RPART, reps, M / 2);
  };

  build_graph(NNODES);
  conv(NNODES, x, 256, P0, lin0_w, lin0_b, 0);
  conv(NNODES, P0, 128, P1, lin_w, lin_b, 1);
  pool(0, P1, P0, NNODES, 1024, REPS0);
  build_graph(16384);
  conv(16384, P0, 128, P1, lin_w + 128 * 128, lin_b + 128, 2);
  conv(16384, P1, 128, P0, lin_w + 2 * 128 * 128, lin_b + 2 * 128, 3);
  pool(1, P0, P1, 16384, 512, REPS1);

  final_out<<<NB * 256 / 256, 256, 0, stream>>>(REPS0, REPS1, out);

  if (hipGetLastError() != hipSuccess) {
    hipMemsetAsync(d_out, 0x45, (size_t)out_size * 4, stream);
  }
}